// Round 1
// baseline (2735.938 us; speedup 1.0000x reference)
//
#include <hip/hip_runtime.h>
#include <hip/hip_bf16.h>
#include <math.h>

#define N_NODES 100000
#define N_EDGES 3200000
#define FEAT 512
#define HID 256
#define CLS 64
#define K_ITER 10

// ---------- edge index access (int32 or int64, detected at runtime) ----------
__device__ __forceinline__ int edge_at(const void* e, int is64, long long idx) {
    return is64 ? (int)((const long long*)e)[idx] : ((const int*)e)[idx];
}

// Detect int64: if stored as int64 little-endian, every odd 32-bit word (high
// half) is 0 (values in [0, 100000)). For int32 data those words are random
// edge indices, ~never all zero across 4096 samples.
__global__ void k_detect(const unsigned* __restrict__ e, int* __restrict__ flag) {
    __shared__ unsigned s[256];
    unsigned v = 0;
    for (int i = threadIdx.x; i < 4096; i += 256) v |= e[2 * i + 1];
    s[threadIdx.x] = v;
    __syncthreads();
    for (int off = 128; off; off >>= 1) {
        if (threadIdx.x < off) s[threadIdx.x] |= s[threadIdx.x + off];
        __syncthreads();
    }
    if (threadIdx.x == 0) flag[0] = (s[0] == 0) ? 1 : 0;
}

// ---------- degree + row-count init (self loops contribute 1 each) ----------
__global__ void k_init(int* __restrict__ deg, int* __restrict__ cnt) {
    int i = blockIdx.x * 256 + threadIdx.x;
    if (i < N_NODES) { deg[i] = 1; cnt[i] = 1; }
    else if (i == N_NODES) { cnt[i] = 0; }
}

__global__ void k_hist(const void* __restrict__ e, const int* __restrict__ flag,
                       int* __restrict__ deg, int* __restrict__ cnt) {
    long long i = (long long)blockIdx.x * 256 + threadIdx.x;
    if (i >= N_EDGES) return;
    int is64 = flag[0];
    int r = edge_at(e, is64, i);
    int c = edge_at(e, is64, (long long)N_EDGES + i);
    atomicAdd(&cnt[r], 1);   // rows = segment ids for aggregation
    atomicAdd(&deg[c], 1);   // degree computed over col in reference
}

__global__ void k_dinv(const int* __restrict__ deg, float* __restrict__ dinv) {
    int i = blockIdx.x * 256 + threadIdx.x;
    if (i < N_NODES) dinv[i] = rsqrtf((float)deg[i]);
}

// ---------- exclusive scan over cnt[0..N_NODES] (100001 entries) ----------
__global__ void k_scan1(const int* __restrict__ cnt, int* __restrict__ offs,
                        int* __restrict__ bsum, int n) {
    __shared__ int s[256];
    int i = blockIdx.x * 256 + threadIdx.x;
    int v = (i < n) ? cnt[i] : 0;
    s[threadIdx.x] = v;
    __syncthreads();
    for (int off = 1; off < 256; off <<= 1) {
        int t = (threadIdx.x >= off) ? s[threadIdx.x - off] : 0;
        __syncthreads();
        s[threadIdx.x] += t;
        __syncthreads();
    }
    if (i < n) offs[i] = s[threadIdx.x] - v;  // exclusive within block
    if (threadIdx.x == 255) bsum[blockIdx.x] = s[255];
}

__global__ void k_scan2(int* __restrict__ bsum, int nb) {
    __shared__ int s[512];
    int v = (threadIdx.x < nb) ? bsum[threadIdx.x] : 0;
    s[threadIdx.x] = v;
    __syncthreads();
    for (int off = 1; off < 512; off <<= 1) {
        int t = (threadIdx.x >= off) ? s[threadIdx.x - off] : 0;
        __syncthreads();
        s[threadIdx.x] += t;
        __syncthreads();
    }
    if (threadIdx.x < nb) bsum[threadIdx.x] = s[threadIdx.x] - v;  // exclusive
}

__global__ void k_scan3(int* __restrict__ offs, const int* __restrict__ bsum,
                        int* __restrict__ cur, int n) {
    int i = blockIdx.x * 256 + threadIdx.x;
    if (i < n) {
        int o = offs[i] + bsum[i >> 8];
        offs[i] = o;
        if (i < N_NODES) cur[i] = o;
    }
}

// ---------- scatter edges into CSR (dst-major), weight = dinv[r]*dinv[c] ----------
__global__ void k_scatter(const void* __restrict__ e, const int* __restrict__ flag,
                          const float* __restrict__ dinv, int* __restrict__ cur,
                          int* __restrict__ ccol, float* __restrict__ cw) {
    long long i = (long long)blockIdx.x * 256 + threadIdx.x;
    if (i >= (long long)N_EDGES + N_NODES) return;
    int is64 = flag[0];
    int r, c;
    if (i < N_EDGES) {
        r = edge_at(e, is64, i);
        c = edge_at(e, is64, (long long)N_EDGES + i);
    } else {
        r = c = (int)(i - N_EDGES);
    }
    float w = dinv[r] * dinv[c];
    int pos = atomicAdd(&cur[r], 1);
    ccol[pos] = c;
    cw[pos] = w;
}

// ---------- fp32 tiled GEMM: C[M,N] = A[M,K] @ B[K,N] + bias, optional ReLU ----------
// BM=64, BN=64, BK=16, 256 threads, 4x4 microtile per thread.
template <bool RELU>
__global__ __launch_bounds__(256) void k_gemm(const float* __restrict__ A,
                                              const float* __restrict__ B,
                                              const float* __restrict__ bias,
                                              float* __restrict__ C,
                                              int M, int N, int K) {
    __shared__ float As[16][68];
    __shared__ float Bs[16][68];
    const int tid = threadIdx.x;
    const int tx = tid & 15, ty = tid >> 4;
    const int bx = blockIdx.x, by = blockIdx.y;

    float acc[4][4] = {};
    const int arow = by * 64 + (tid >> 2);
    const int ak0 = (tid & 3) * 4;
    const int brow = tid >> 4;
    const int bcol = bx * 64 + (tid & 15) * 4;

    for (int kt = 0; kt < K; kt += 16) {
        float4 a = make_float4(0.f, 0.f, 0.f, 0.f);
        if (arow < M) a = *(const float4*)&A[(long long)arow * K + kt + ak0];
        As[ak0 + 0][tid >> 2] = a.x;
        As[ak0 + 1][tid >> 2] = a.y;
        As[ak0 + 2][tid >> 2] = a.z;
        As[ak0 + 3][tid >> 2] = a.w;
        float4 b = *(const float4*)&B[(long long)(kt + brow) * N + bcol];
        *(float4*)&Bs[brow][(tid & 15) * 4] = b;
        __syncthreads();
#pragma unroll
        for (int k = 0; k < 16; k++) {
            float4 av = *(const float4*)&As[k][ty * 4];
            float4 bv = *(const float4*)&Bs[k][tx * 4];
            float am[4] = {av.x, av.y, av.z, av.w};
            float bm[4] = {bv.x, bv.y, bv.z, bv.w};
#pragma unroll
            for (int i = 0; i < 4; i++)
#pragma unroll
                for (int j = 0; j < 4; j++) acc[i][j] += am[i] * bm[j];
        }
        __syncthreads();
    }

#pragma unroll
    for (int i = 0; i < 4; i++) {
        int r = by * 64 + ty * 4 + i;
        if (r >= M) break;
        int cbase = bx * 64 + tx * 4;
        float4 v;
        float* vp = (float*)&v;
#pragma unroll
        for (int j = 0; j < 4; j++) {
            float t = acc[i][j] + bias[cbase + j];
            if (RELU) t = fmaxf(t, 0.f);
            vp[j] = t;
        }
        *(float4*)&C[(long long)r * N + cbase] = v;
    }
}

// ---------- propagation: one wave per node, lane = class ----------
__global__ __launch_bounds__(256) void k_prop(const int* __restrict__ ccol,
                                              const float* __restrict__ cw,
                                              const int* __restrict__ offs,
                                              const float* __restrict__ src,
                                              const float* __restrict__ h,
                                              float* __restrict__ dst, int last) {
    int wid = (blockIdx.x << 2) + (threadIdx.x >> 6);
    int lane = threadIdx.x & 63;
    if (wid >= N_NODES) return;
    int e0 = offs[wid], e1 = offs[wid + 1];
    float acc = 0.f;
    int e = e0;
    for (; e + 1 < e1; e += 2) {
        int c0 = ccol[e], c1 = ccol[e + 1];
        float w0 = cw[e], w1 = cw[e + 1];
        float v0 = src[(long long)c0 * CLS + lane];
        float v1 = src[(long long)c1 * CLS + lane];
        acc += w0 * v0;
        acc += w1 * v1;
    }
    if (e < e1) acc += cw[e] * src[(long long)ccol[e] * CLS + lane];

    float o = 0.9f * acc + 0.1f * h[(long long)wid * CLS + lane];
    if (!last) {
        dst[(long long)wid * CLS + lane] = o;
    } else {
        float m = o;
        for (int off = 32; off; off >>= 1) m = fmaxf(m, __shfl_xor(m, off));
        float s = expf(o - m);
        for (int off = 32; off; off >>= 1) s += __shfl_xor(s, off);
        dst[(long long)wid * CLS + lane] = o - m - logf(s);
    }
}

extern "C" void kernel_launch(void* const* d_in, const int* in_sizes, int n_in,
                              void* d_out, int out_size, void* d_ws, size_t ws_size,
                              hipStream_t stream) {
    const float* x  = (const float*)d_in[0];
    const void*  ei = d_in[1];
    const float* W1 = (const float*)d_in[2];
    const float* b1 = (const float*)d_in[3];
    const float* W2 = (const float*)d_in[4];
    const float* b2 = (const float*)d_in[5];
    float* out = (float*)d_out;

    // workspace carve
    char* p = (char*)d_ws;
    size_t off = 0;
    auto alloc = [&](size_t bytes) {
        char* q = p + off;
        off = (off + bytes + 255) & ~(size_t)255;
        return q;
    };
    int*   flag = (int*)alloc(16);
    int*   deg  = (int*)alloc((size_t)N_NODES * 4);
    float* dinv = (float*)alloc((size_t)N_NODES * 4);
    int*   cnt  = (int*)alloc((size_t)(N_NODES + 1) * 4);
    int*   offs = (int*)alloc((size_t)(N_NODES + 1) * 4);
    int*   bsum = (int*)alloc(512 * 4);
    int*   cur  = (int*)alloc((size_t)N_NODES * 4);
    int*   ccol = (int*)alloc((size_t)(N_EDGES + N_NODES) * 4);
    float* cw   = (float*)alloc((size_t)(N_EDGES + N_NODES) * 4);
    float* h    = (float*)alloc((size_t)N_NODES * CLS * 4);
    float* bufA = (float*)alloc((size_t)N_NODES * CLS * 4);
    float* bufB = (float*)alloc((size_t)N_NODES * CLS * 4);
    float* h1   = (float*)alloc((size_t)N_NODES * HID * 4);
    (void)ws_size;

    // graph build
    k_detect<<<1, 256, 0, stream>>>((const unsigned*)ei, flag);
    k_init<<<(N_NODES + 256) / 256, 256, 0, stream>>>(deg, cnt);
    k_hist<<<(N_EDGES + 255) / 256, 256, 0, stream>>>(ei, flag, deg, cnt);
    k_dinv<<<(N_NODES + 255) / 256, 256, 0, stream>>>(deg, dinv);
    const int nscan = N_NODES + 1;
    const int nblk = (nscan + 255) / 256;  // 392
    k_scan1<<<nblk, 256, 0, stream>>>(cnt, offs, bsum, nscan);
    k_scan2<<<1, 512, 0, stream>>>(bsum, nblk);
    k_scan3<<<nblk, 256, 0, stream>>>(offs, bsum, cur, nscan);
    k_scatter<<<(N_EDGES + N_NODES + 255) / 256, 256, 0, stream>>>(ei, flag, dinv, cur, ccol, cw);

    // dense layers
    k_gemm<true><<<dim3(HID / 64, (N_NODES + 63) / 64), 256, 0, stream>>>(
        x, W1, b1, h1, N_NODES, HID, FEAT);
    k_gemm<false><<<dim3(CLS / 64, (N_NODES + 63) / 64), 256, 0, stream>>>(
        h1, W2, b2, h, N_NODES, CLS, HID);

    // K propagation steps; final step fuses log_softmax and writes d_out
    const int pgrid = (N_NODES + 3) / 4;
    float* ping[2] = {bufA, bufB};
    for (int it = 0; it < K_ITER; it++) {
        const float* src = (it == 0) ? h : ping[(it - 1) & 1];
        float* dst = (it == K_ITER - 1) ? out : ping[it & 1];
        k_prop<<<pgrid, 256, 0, stream>>>(ccol, cw, offs, src, h, dst, it == K_ITER - 1);
    }
}

// Round 2
// 1890.037 us; speedup vs baseline: 1.4476x; 1.4476x over previous
//
#include <hip/hip_runtime.h>
#include <hip/hip_bf16.h>
#include <math.h>

#define N_NODES 100000
#define N_EDGES 3200000
#define FEAT 512
#define HID 256
#define CLS 64
#define K_ITER 10

typedef _Float16 half8 __attribute__((ext_vector_type(8)));
typedef float f32x4 __attribute__((ext_vector_type(4)));

// ---------- edge index access (int32 or int64, detected at runtime) ----------
__device__ __forceinline__ int edge_at(const void* e, int is64, long long idx) {
    return is64 ? (int)((const long long*)e)[idx] : ((const int*)e)[idx];
}

__global__ void k_detect(const unsigned* __restrict__ e, int* __restrict__ flag) {
    __shared__ unsigned s[256];
    unsigned v = 0;
    for (int i = threadIdx.x; i < 4096; i += 256) v |= e[2 * i + 1];
    s[threadIdx.x] = v;
    __syncthreads();
    for (int off = 128; off; off >>= 1) {
        if (threadIdx.x < off) s[threadIdx.x] |= s[threadIdx.x + off];
        __syncthreads();
    }
    if (threadIdx.x == 0) flag[0] = (s[0] == 0) ? 1 : 0;
}

__global__ void k_init(int* __restrict__ deg, int* __restrict__ cnt) {
    int i = blockIdx.x * 256 + threadIdx.x;
    if (i < N_NODES) { deg[i] = 1; cnt[i] = 1; }
    else if (i == N_NODES) { cnt[i] = 0; }
}

__global__ void k_hist(const void* __restrict__ e, const int* __restrict__ flag,
                       int* __restrict__ deg, int* __restrict__ cnt) {
    long long i = (long long)blockIdx.x * 256 + threadIdx.x;
    if (i >= N_EDGES) return;
    int is64 = flag[0];
    int r = edge_at(e, is64, i);
    int c = edge_at(e, is64, (long long)N_EDGES + i);
    atomicAdd(&cnt[r], 1);
    atomicAdd(&deg[c], 1);
}

__global__ void k_dinv(const int* __restrict__ deg, float* __restrict__ dinv) {
    int i = blockIdx.x * 256 + threadIdx.x;
    if (i < N_NODES) dinv[i] = rsqrtf((float)deg[i]);
}

// ---------- exclusive scan over cnt[0..N_NODES] ----------
__global__ void k_scan1(const int* __restrict__ cnt, int* __restrict__ offs,
                        int* __restrict__ bsum, int n) {
    __shared__ int s[256];
    int i = blockIdx.x * 256 + threadIdx.x;
    int v = (i < n) ? cnt[i] : 0;
    s[threadIdx.x] = v;
    __syncthreads();
    for (int off = 1; off < 256; off <<= 1) {
        int t = (threadIdx.x >= off) ? s[threadIdx.x - off] : 0;
        __syncthreads();
        s[threadIdx.x] += t;
        __syncthreads();
    }
    if (i < n) offs[i] = s[threadIdx.x] - v;
    if (threadIdx.x == 255) bsum[blockIdx.x] = s[255];
}

__global__ void k_scan2(int* __restrict__ bsum, int nb) {
    __shared__ int s[512];
    int v = (threadIdx.x < nb) ? bsum[threadIdx.x] : 0;
    s[threadIdx.x] = v;
    __syncthreads();
    for (int off = 1; off < 512; off <<= 1) {
        int t = (threadIdx.x >= off) ? s[threadIdx.x - off] : 0;
        __syncthreads();
        s[threadIdx.x] += t;
        __syncthreads();
    }
    if (threadIdx.x < nb) bsum[threadIdx.x] = s[threadIdx.x] - v;
}

__global__ void k_scan3(int* __restrict__ offs, const int* __restrict__ bsum,
                        int* __restrict__ cur, int n) {
    int i = blockIdx.x * 256 + threadIdx.x;
    if (i < n) {
        int o = offs[i] + bsum[i >> 8];
        offs[i] = o;
        if (i < N_NODES) cur[i] = o;
    }
}

__global__ void k_scatter(const void* __restrict__ e, const int* __restrict__ flag,
                          const float* __restrict__ dinv, int* __restrict__ cur,
                          int* __restrict__ ccol, float* __restrict__ cw) {
    long long i = (long long)blockIdx.x * 256 + threadIdx.x;
    if (i >= (long long)N_EDGES + N_NODES) return;
    int is64 = flag[0];
    int r, c;
    if (i < N_EDGES) {
        r = edge_at(e, is64, i);
        c = edge_at(e, is64, (long long)N_EDGES + i);
    } else {
        r = c = (int)(i - N_EDGES);
    }
    float w = dinv[r] * dinv[c];
    int pos = atomicAdd(&cur[r], 1);
    ccol[pos] = c;
    cw[pos] = w;
}

// ---------- weight transpose + fp16 convert ----------
// W1T[n][k] = (fp16)W1[k][n]  (256x512); W2T[n][k] = (fp16)W2[k][n] (64x256)
__global__ void k_cvtW(const float* __restrict__ W1, const float* __restrict__ W2,
                       _Float16* __restrict__ W1T, _Float16* __restrict__ W2T) {
    int i = blockIdx.x * 256 + threadIdx.x;
    if (i < 256 * 512) {
        int n = i >> 9, k = i & 511;
        W1T[i] = (_Float16)W1[k * 256 + n];
    }
    if (i < 64 * 256) {
        int n = i >> 8, k = i & 255;
        W2T[i] = (_Float16)W2[k * 64 + n];
    }
}

// swizzle helper: physical granule for (row, logical granule)
__device__ __forceinline__ int swz(int row, int g) {
    return g ^ (row & 3) ^ ((row >> 2) & 3);
}

// ---------- GEMM1: h1[M][256](fp16) = relu(x[M][512](fp32) @ W1 + b1) ----------
// BM=128, BN=256, BK=32, 512 threads (8 waves, 2Mx4N), MFMA 16x16x32 f16.
__global__ __launch_bounds__(512) void k_gemm1(const float* __restrict__ A,
                                               const _Float16* __restrict__ BT,
                                               const float* __restrict__ bias,
                                               _Float16* __restrict__ C, int M) {
    __shared__ __align__(16) char lds[8192 + 16384];  // As[128][32]h, Bs[256][32]h
    const int t = threadIdx.x;
    const int wid = t >> 6, lane = t & 63;
    const int wr = wid >> 2, wc = wid & 3;
    const int srow = t >> 2, sg = t & 3;
    const int fr = lane & 15, fg = lane >> 4;
    const long long by = blockIdx.x;

    f32x4 acc[4][4] = {};
    const long long arow = by * 128 + srow;
    const bool avalid = (arow < M);
    const float* ap0 = A + arow * FEAT + sg * 8;

    for (int kt = 0; kt < FEAT; kt += 32) {
        // stage A (fp32 -> fp16)
        float4 a0 = make_float4(0.f, 0.f, 0.f, 0.f), a1 = a0;
        if (avalid) {
            const float* ap = ap0 + kt;
            a0 = *(const float4*)ap;
            a1 = *(const float4*)(ap + 4);
        }
        half8 ah;
        ah[0] = (_Float16)a0.x; ah[1] = (_Float16)a0.y;
        ah[2] = (_Float16)a0.z; ah[3] = (_Float16)a0.w;
        ah[4] = (_Float16)a1.x; ah[5] = (_Float16)a1.y;
        ah[6] = (_Float16)a1.z; ah[7] = (_Float16)a1.w;
        *(half8*)(lds + srow * 64 + swz(srow, sg) * 16) = ah;
        // stage B (fp16 passthrough), 2 chunks
#pragma unroll
        for (int rep = 0; rep < 2; rep++) {
            int brow = rep * 128 + srow;
            half8 bh = *(const half8*)(BT + brow * FEAT + kt + sg * 8);
            *(half8*)(lds + 8192 + brow * 64 + swz(brow, sg) * 16) = bh;
        }
        __syncthreads();

        half8 af[4], bf[4];
#pragma unroll
        for (int mi = 0; mi < 4; mi++) {
            int r = wr * 64 + mi * 16 + fr;
            af[mi] = *(const half8*)(lds + r * 64 + swz(r, fg) * 16);
        }
#pragma unroll
        for (int nj = 0; nj < 4; nj++) {
            int r = wc * 64 + nj * 16 + fr;
            bf[nj] = *(const half8*)(lds + 8192 + r * 64 + swz(r, fg) * 16);
        }
#pragma unroll
        for (int mi = 0; mi < 4; mi++)
#pragma unroll
            for (int nj = 0; nj < 4; nj++)
                acc[mi][nj] = __builtin_amdgcn_mfma_f32_16x16x32_f16(af[mi], bf[nj], acc[mi][nj], 0, 0, 0);
        __syncthreads();
    }

#pragma unroll
    for (int mi = 0; mi < 4; mi++) {
#pragma unroll
        for (int nj = 0; nj < 4; nj++) {
            int col = wc * 64 + nj * 16 + fr;
            float bv = bias[col];
#pragma unroll
            for (int r = 0; r < 4; r++) {
                long long row = by * 128 + wr * 64 + mi * 16 + fg * 4 + r;
                if (row < M) {
                    float v = fmaxf(acc[mi][nj][r] + bv, 0.f);
                    C[row * HID + col] = (_Float16)v;
                }
            }
        }
    }
}

// ---------- GEMM2: h[M][64](fp32) = h1[M][256](fp16) @ W2 + b2 ----------
// BM=256, BN=64, BK=32, 512 threads (8 waves, 4Mx2N).
__global__ __launch_bounds__(512) void k_gemm2(const _Float16* __restrict__ A,
                                               const _Float16* __restrict__ BT,
                                               const float* __restrict__ bias,
                                               float* __restrict__ C, int M) {
    __shared__ __align__(16) char lds[16384 + 4096];  // As[256][32]h, Bs[64][32]h
    const int t = threadIdx.x;
    const int wid = t >> 6, lane = t & 63;
    const int wr = wid >> 1, wc = wid & 1;
    const int srow = t >> 2, sg = t & 3;
    const int fr = lane & 15, fg = lane >> 4;
    const long long bm = blockIdx.x;

    f32x4 acc[4][2] = {};

    for (int kt = 0; kt < HID; kt += 32) {
#pragma unroll
        for (int rep = 0; rep < 2; rep++) {
            int ar = rep * 128 + srow;
            long long grow = bm * 256 + ar;
            if (grow >= M) grow = M - 1;  // clamp: result rows discarded
            half8 ah = *(const half8*)(A + grow * HID + kt + sg * 8);
            *(half8*)(lds + ar * 64 + swz(ar, sg) * 16) = ah;
        }
        if (t < 256) {
            int br = t >> 2;
            half8 bh = *(const half8*)(BT + br * HID + kt + sg * 8);
            *(half8*)(lds + 16384 + br * 64 + swz(br, sg) * 16) = bh;
        }
        __syncthreads();

        half8 af[4], bf[2];
#pragma unroll
        for (int mi = 0; mi < 4; mi++) {
            int r = wr * 64 + mi * 16 + fr;
            af[mi] = *(const half8*)(lds + r * 64 + swz(r, fg) * 16);
        }
#pragma unroll
        for (int nj = 0; nj < 2; nj++) {
            int r = wc * 32 + nj * 16 + fr;
            bf[nj] = *(const half8*)(lds + 16384 + r * 64 + swz(r, fg) * 16);
        }
#pragma unroll
        for (int mi = 0; mi < 4; mi++)
#pragma unroll
            for (int nj = 0; nj < 2; nj++)
                acc[mi][nj] = __builtin_amdgcn_mfma_f32_16x16x32_f16(af[mi], bf[nj], acc[mi][nj], 0, 0, 0);
        __syncthreads();
    }

#pragma unroll
    for (int mi = 0; mi < 4; mi++) {
#pragma unroll
        for (int nj = 0; nj < 2; nj++) {
            int col = wc * 32 + nj * 16 + fr;
            float bv = bias[col];
#pragma unroll
            for (int r = 0; r < 4; r++) {
                long long row = bm * 256 + wr * 64 + mi * 16 + fg * 4 + r;
                if (row < M) C[row * CLS + col] = acc[mi][nj][r] + bv;
            }
        }
    }
}

// ---------- propagation: one wave per node, lane = class, 4-way unrolled ----------
__global__ __launch_bounds__(256) void k_prop(const int* __restrict__ ccol,
                                              const float* __restrict__ cw,
                                              const int* __restrict__ offs,
                                              const float* __restrict__ src,
                                              const float* __restrict__ h,
                                              float* __restrict__ dst, int last) {
    int wid = (blockIdx.x << 2) + (threadIdx.x >> 6);
    int lane = threadIdx.x & 63;
    if (wid >= N_NODES) return;
    int e0 = offs[wid], e1 = offs[wid + 1];
    float acc = 0.f;
    int e = e0;
    for (; e + 3 < e1; e += 4) {
        int c0 = ccol[e], c1 = ccol[e + 1], c2 = ccol[e + 2], c3 = ccol[e + 3];
        float w0 = cw[e], w1 = cw[e + 1], w2 = cw[e + 2], w3 = cw[e + 3];
        float v0 = src[(long long)c0 * CLS + lane];
        float v1 = src[(long long)c1 * CLS + lane];
        float v2 = src[(long long)c2 * CLS + lane];
        float v3 = src[(long long)c3 * CLS + lane];
        acc += w0 * v0; acc += w1 * v1; acc += w2 * v2; acc += w3 * v3;
    }
    for (; e < e1; e++) acc += cw[e] * src[(long long)ccol[e] * CLS + lane];

    float o = 0.9f * acc + 0.1f * h[(long long)wid * CLS + lane];
    if (!last) {
        dst[(long long)wid * CLS + lane] = o;
    } else {
        float m = o;
        for (int off = 32; off; off >>= 1) m = fmaxf(m, __shfl_xor(m, off));
        float s = expf(o - m);
        for (int off = 32; off; off >>= 1) s += __shfl_xor(s, off);
        dst[(long long)wid * CLS + lane] = o - m - logf(s);
    }
}

extern "C" void kernel_launch(void* const* d_in, const int* in_sizes, int n_in,
                              void* d_out, int out_size, void* d_ws, size_t ws_size,
                              hipStream_t stream) {
    const float* x  = (const float*)d_in[0];
    const void*  ei = d_in[1];
    const float* W1 = (const float*)d_in[2];
    const float* b1 = (const float*)d_in[3];
    const float* W2 = (const float*)d_in[4];
    const float* b2 = (const float*)d_in[5];
    float* out = (float*)d_out;

    char* p = (char*)d_ws;
    size_t off = 0;
    auto alloc = [&](size_t bytes) {
        char* q = p + off;
        off = (off + bytes + 255) & ~(size_t)255;
        return q;
    };
    int*      flag = (int*)alloc(16);
    int*      deg  = (int*)alloc((size_t)N_NODES * 4);
    float*    dinv = (float*)alloc((size_t)N_NODES * 4);
    int*      cnt  = (int*)alloc((size_t)(N_NODES + 1) * 4);
    int*      offs = (int*)alloc((size_t)(N_NODES + 1) * 4);
    int*      bsum = (int*)alloc(512 * 4);
    int*      cur  = (int*)alloc((size_t)N_NODES * 4);
    int*      ccol = (int*)alloc((size_t)(N_EDGES + N_NODES) * 4);
    float*    cw   = (float*)alloc((size_t)(N_EDGES + N_NODES) * 4);
    float*    h    = (float*)alloc((size_t)N_NODES * CLS * 4);
    float*    bufA = (float*)alloc((size_t)N_NODES * CLS * 4);
    float*    bufB = (float*)alloc((size_t)N_NODES * CLS * 4);
    _Float16* h1   = (_Float16*)alloc((size_t)N_NODES * HID * 2);
    _Float16* W1T  = (_Float16*)alloc((size_t)HID * FEAT * 2);
    _Float16* W2T  = (_Float16*)alloc((size_t)CLS * HID * 2);
    (void)ws_size;

    // graph build
    k_detect<<<1, 256, 0, stream>>>((const unsigned*)ei, flag);
    k_init<<<(N_NODES + 256) / 256, 256, 0, stream>>>(deg, cnt);
    k_hist<<<(N_EDGES + 255) / 256, 256, 0, stream>>>(ei, flag, deg, cnt);
    k_dinv<<<(N_NODES + 255) / 256, 256, 0, stream>>>(deg, dinv);
    const int nscan = N_NODES + 1;
    const int nblk = (nscan + 255) / 256;
    k_scan1<<<nblk, 256, 0, stream>>>(cnt, offs, bsum, nscan);
    k_scan2<<<1, 512, 0, stream>>>(bsum, nblk);
    k_scan3<<<nblk, 256, 0, stream>>>(offs, bsum, cur, nscan);
    k_scatter<<<(N_EDGES + N_NODES + 255) / 256, 256, 0, stream>>>(ei, flag, dinv, cur, ccol, cw);

    // dense layers (fp16 MFMA)
    k_cvtW<<<512, 256, 0, stream>>>(W1, W2, W1T, W2T);
    k_gemm1<<<(N_NODES + 127) / 128, 512, 0, stream>>>(x, W1T, b1, h1, N_NODES);
    k_gemm2<<<(N_NODES + 255) / 256, 512, 0, stream>>>(h1, W2T, b2, h, N_NODES);

    // K propagation steps; final step fuses log_softmax
    const int pgrid = (N_NODES + 3) / 4;
    float* ping[2] = {bufA, bufB};
    for (int it = 0; it < K_ITER; it++) {
        const float* src = (it == 0) ? h : ping[(it - 1) & 1];
        float* dst = (it == K_ITER - 1) ? out : ping[it & 1];
        k_prop<<<pgrid, 256, 0, stream>>>(ccol, cw, offs, src, h, dst, it == K_ITER - 1);
    }
}

// Round 3
// 1713.084 us; speedup vs baseline: 1.5971x; 1.1033x over previous
//
#include <hip/hip_runtime.h>
#include <hip/hip_bf16.h>
#include <math.h>

#define N_NODES 100000
#define N_EDGES 3200000
#define FEAT 512
#define HID 256
#define CLS 64
#define K_ITER 10

typedef _Float16 half8 __attribute__((ext_vector_type(8)));
typedef float f32x4 __attribute__((ext_vector_type(4)));

// ---------- edge index access (int32 or int64, detected at runtime) ----------
__device__ __forceinline__ int edge_at(const void* e, int is64, long long idx) {
    return is64 ? (int)((const long long*)e)[idx] : ((const int*)e)[idx];
}

__global__ void k_detect(const unsigned* __restrict__ e, int* __restrict__ flag) {
    __shared__ unsigned s[256];
    unsigned v = 0;
    for (int i = threadIdx.x; i < 4096; i += 256) v |= e[2 * i + 1];
    s[threadIdx.x] = v;
    __syncthreads();
    for (int off = 128; off; off >>= 1) {
        if (threadIdx.x < off) s[threadIdx.x] |= s[threadIdx.x + off];
        __syncthreads();
    }
    if (threadIdx.x == 0) flag[0] = (s[0] == 0) ? 1 : 0;
}

__global__ void k_init(int* __restrict__ deg, int* __restrict__ cnt) {
    int i = blockIdx.x * 256 + threadIdx.x;
    if (i < N_NODES) { deg[i] = 1; cnt[i] = 1; }
    else if (i == N_NODES) { cnt[i] = 0; }
}

__global__ void k_hist(const void* __restrict__ e, const int* __restrict__ flag,
                       int* __restrict__ deg, int* __restrict__ cnt) {
    long long i = (long long)blockIdx.x * 256 + threadIdx.x;
    if (i >= N_EDGES) return;
    int is64 = flag[0];
    int r = edge_at(e, is64, i);
    int c = edge_at(e, is64, (long long)N_EDGES + i);
    atomicAdd(&cnt[r], 1);
    atomicAdd(&deg[c], 1);
}

__global__ void k_dinv(const int* __restrict__ deg, float* __restrict__ dinv) {
    int i = blockIdx.x * 256 + threadIdx.x;
    if (i < N_NODES) dinv[i] = rsqrtf((float)deg[i]);
}

// ---------- exclusive scan over cnt[0..N_NODES] ----------
__global__ void k_scan1(const int* __restrict__ cnt, int* __restrict__ offs,
                        int* __restrict__ bsum, int n) {
    __shared__ int s[256];
    int i = blockIdx.x * 256 + threadIdx.x;
    int v = (i < n) ? cnt[i] : 0;
    s[threadIdx.x] = v;
    __syncthreads();
    for (int off = 1; off < 256; off <<= 1) {
        int t = (threadIdx.x >= off) ? s[threadIdx.x - off] : 0;
        __syncthreads();
        s[threadIdx.x] += t;
        __syncthreads();
    }
    if (i < n) offs[i] = s[threadIdx.x] - v;
    if (threadIdx.x == 255) bsum[blockIdx.x] = s[255];
}

__global__ void k_scan2(int* __restrict__ bsum, int nb) {
    __shared__ int s[512];
    int v = (threadIdx.x < nb) ? bsum[threadIdx.x] : 0;
    s[threadIdx.x] = v;
    __syncthreads();
    for (int off = 1; off < 512; off <<= 1) {
        int t = (threadIdx.x >= off) ? s[threadIdx.x - off] : 0;
        __syncthreads();
        s[threadIdx.x] += t;
        __syncthreads();
    }
    if (threadIdx.x < nb) bsum[threadIdx.x] = s[threadIdx.x] - v;
}

__global__ void k_scan3(int* __restrict__ offs, const int* __restrict__ bsum,
                        int* __restrict__ cur, int n) {
    int i = blockIdx.x * 256 + threadIdx.x;
    if (i < n) {
        int o = offs[i] + bsum[i >> 8];
        offs[i] = o;
        if (i < N_NODES) cur[i] = o;
    }
}

// ---------- scatter edges into CSR (dst-major); col index only ----------
__global__ void k_scatter(const void* __restrict__ e, const int* __restrict__ flag,
                          int* __restrict__ cur, int* __restrict__ ccol) {
    long long i = (long long)blockIdx.x * 256 + threadIdx.x;
    if (i >= (long long)N_EDGES + N_NODES) return;
    int is64 = flag[0];
    int r, c;
    if (i < N_EDGES) {
        r = edge_at(e, is64, i);
        c = edge_at(e, is64, (long long)N_EDGES + i);
    } else {
        r = c = (int)(i - N_EDGES);
    }
    int pos = atomicAdd(&cur[r], 1);
    ccol[pos] = c;
}

// ---------- weight transpose + fp16 convert ----------
__global__ void k_cvtW(const float* __restrict__ W1, const float* __restrict__ W2,
                       _Float16* __restrict__ W1T, _Float16* __restrict__ W2T) {
    int i = blockIdx.x * 256 + threadIdx.x;
    if (i < 256 * 512) {
        int n = i >> 9, k = i & 511;
        W1T[i] = (_Float16)W1[k * 256 + n];
    }
    if (i < 64 * 256) {
        int n = i >> 8, k = i & 255;
        W2T[i] = (_Float16)W2[k * 64 + n];
    }
}

// swizzle helper: physical granule for (row, logical granule)
__device__ __forceinline__ int swz(int row, int g) {
    return g ^ (row & 3) ^ ((row >> 2) & 3);
}

// ---------- GEMM1: h1[M][256](fp16) = relu(x[M][512](fp32) @ W1 + b1) ----------
__global__ __launch_bounds__(512) void k_gemm1(const float* __restrict__ A,
                                               const _Float16* __restrict__ BT,
                                               const float* __restrict__ bias,
                                               _Float16* __restrict__ C, int M) {
    __shared__ __align__(16) char lds[8192 + 16384];
    const int t = threadIdx.x;
    const int wid = t >> 6, lane = t & 63;
    const int wr = wid >> 2, wc = wid & 3;
    const int srow = t >> 2, sg = t & 3;
    const int fr = lane & 15, fg = lane >> 4;
    const long long by = blockIdx.x;

    f32x4 acc[4][4] = {};
    const long long arow = by * 128 + srow;
    const bool avalid = (arow < M);
    const float* ap0 = A + arow * FEAT + sg * 8;

    for (int kt = 0; kt < FEAT; kt += 32) {
        float4 a0 = make_float4(0.f, 0.f, 0.f, 0.f), a1 = a0;
        if (avalid) {
            const float* ap = ap0 + kt;
            a0 = *(const float4*)ap;
            a1 = *(const float4*)(ap + 4);
        }
        half8 ah;
        ah[0] = (_Float16)a0.x; ah[1] = (_Float16)a0.y;
        ah[2] = (_Float16)a0.z; ah[3] = (_Float16)a0.w;
        ah[4] = (_Float16)a1.x; ah[5] = (_Float16)a1.y;
        ah[6] = (_Float16)a1.z; ah[7] = (_Float16)a1.w;
        *(half8*)(lds + srow * 64 + swz(srow, sg) * 16) = ah;
#pragma unroll
        for (int rep = 0; rep < 2; rep++) {
            int brow = rep * 128 + srow;
            half8 bh = *(const half8*)(BT + brow * FEAT + kt + sg * 8);
            *(half8*)(lds + 8192 + brow * 64 + swz(brow, sg) * 16) = bh;
        }
        __syncthreads();

        half8 af[4], bf[4];
#pragma unroll
        for (int mi = 0; mi < 4; mi++) {
            int r = wr * 64 + mi * 16 + fr;
            af[mi] = *(const half8*)(lds + r * 64 + swz(r, fg) * 16);
        }
#pragma unroll
        for (int nj = 0; nj < 4; nj++) {
            int r = wc * 64 + nj * 16 + fr;
            bf[nj] = *(const half8*)(lds + 8192 + r * 64 + swz(r, fg) * 16);
        }
#pragma unroll
        for (int mi = 0; mi < 4; mi++)
#pragma unroll
            for (int nj = 0; nj < 4; nj++)
                acc[mi][nj] = __builtin_amdgcn_mfma_f32_16x16x32_f16(af[mi], bf[nj], acc[mi][nj], 0, 0, 0);
        __syncthreads();
    }

#pragma unroll
    for (int mi = 0; mi < 4; mi++) {
#pragma unroll
        for (int nj = 0; nj < 4; nj++) {
            int col = wc * 64 + nj * 16 + fr;
            float bv = bias[col];
#pragma unroll
            for (int r = 0; r < 4; r++) {
                long long row = by * 128 + wr * 64 + mi * 16 + fg * 4 + r;
                if (row < M) {
                    float v = fmaxf(acc[mi][nj][r] + bv, 0.f);
                    C[row * HID + col] = (_Float16)v;
                }
            }
        }
    }
}

// ---------- GEMM2: h[M][64](fp16), s0[M][64](fp16 = dinv*h) ----------
__global__ __launch_bounds__(512) void k_gemm2(const _Float16* __restrict__ A,
                                               const _Float16* __restrict__ BT,
                                               const float* __restrict__ bias,
                                               const float* __restrict__ dinv,
                                               _Float16* __restrict__ Hout,
                                               _Float16* __restrict__ S0, int M) {
    __shared__ __align__(16) char lds[16384 + 4096];
    const int t = threadIdx.x;
    const int wid = t >> 6, lane = t & 63;
    const int wr = wid >> 1, wc = wid & 1;
    const int srow = t >> 2, sg = t & 3;
    const int fr = lane & 15, fg = lane >> 4;
    const long long bm = blockIdx.x;

    f32x4 acc[4][2] = {};

    for (int kt = 0; kt < HID; kt += 32) {
#pragma unroll
        for (int rep = 0; rep < 2; rep++) {
            int ar = rep * 128 + srow;
            long long grow = bm * 256 + ar;
            if (grow >= M) grow = M - 1;
            half8 ah = *(const half8*)(A + grow * HID + kt + sg * 8);
            *(half8*)(lds + ar * 64 + swz(ar, sg) * 16) = ah;
        }
        if (t < 256) {
            int br = t >> 2;
            half8 bh = *(const half8*)(BT + br * HID + kt + sg * 8);
            *(half8*)(lds + 16384 + br * 64 + swz(br, sg) * 16) = bh;
        }
        __syncthreads();

        half8 af[4], bf[2];
#pragma unroll
        for (int mi = 0; mi < 4; mi++) {
            int r = wr * 64 + mi * 16 + fr;
            af[mi] = *(const half8*)(lds + r * 64 + swz(r, fg) * 16);
        }
#pragma unroll
        for (int nj = 0; nj < 2; nj++) {
            int r = wc * 32 + nj * 16 + fr;
            bf[nj] = *(const half8*)(lds + 16384 + r * 64 + swz(r, fg) * 16);
        }
#pragma unroll
        for (int mi = 0; mi < 4; mi++)
#pragma unroll
            for (int nj = 0; nj < 2; nj++)
                acc[mi][nj] = __builtin_amdgcn_mfma_f32_16x16x32_f16(af[mi], bf[nj], acc[mi][nj], 0, 0, 0);
        __syncthreads();
    }

#pragma unroll
    for (int mi = 0; mi < 4; mi++) {
#pragma unroll
        for (int nj = 0; nj < 2; nj++) {
            int col = wc * 32 + nj * 16 + fr;
            float bv = bias[col];
#pragma unroll
            for (int r = 0; r < 4; r++) {
                long long row = bm * 256 + wr * 64 + mi * 16 + fg * 4 + r;
                if (row < M) {
                    float o = acc[mi][nj][r] + bv;
                    Hout[row * CLS + col] = (_Float16)o;
                    S0[row * CLS + col] = (_Float16)(dinv[row] * o);
                }
            }
        }
    }
}

// ---------- propagation: one wave per node, lane = class ----------
// state s[c] = dinv[c] * out[c] stored fp16; agg[r] = dinv[r] * sum s[c]
__global__ __launch_bounds__(256) void k_prop(const int* __restrict__ ccol,
                                              const int* __restrict__ offs,
                                              const float* __restrict__ dinv,
                                              const _Float16* __restrict__ src,
                                              const _Float16* __restrict__ h,
                                              _Float16* __restrict__ dst,
                                              float* __restrict__ out, int last) {
    int wid = (blockIdx.x << 2) + (threadIdx.x >> 6);
    int lane = threadIdx.x & 63;
    if (wid >= N_NODES) return;
    int e0 = offs[wid], e1 = offs[wid + 1];
    float acc = 0.f;
    int e = e0;
    for (; e + 3 < e1; e += 4) {
        int c0 = ccol[e], c1 = ccol[e + 1], c2 = ccol[e + 2], c3 = ccol[e + 3];
        float v0 = (float)src[(long long)c0 * CLS + lane];
        float v1 = (float)src[(long long)c1 * CLS + lane];
        float v2 = (float)src[(long long)c2 * CLS + lane];
        float v3 = (float)src[(long long)c3 * CLS + lane];
        acc += v0; acc += v1; acc += v2; acc += v3;
    }
    for (; e < e1; e++) acc += (float)src[(long long)ccol[e] * CLS + lane];

    float dr = dinv[wid];
    float o = 0.9f * dr * acc + 0.1f * (float)h[(long long)wid * CLS + lane];
    if (!last) {
        dst[(long long)wid * CLS + lane] = (_Float16)(dr * o);
    } else {
        float m = o;
        for (int off = 32; off; off >>= 1) m = fmaxf(m, __shfl_xor(m, off));
        float s = expf(o - m);
        for (int off = 32; off; off >>= 1) s += __shfl_xor(s, off);
        out[(long long)wid * CLS + lane] = o - m - logf(s);
    }
}

extern "C" void kernel_launch(void* const* d_in, const int* in_sizes, int n_in,
                              void* d_out, int out_size, void* d_ws, size_t ws_size,
                              hipStream_t stream) {
    const float* x  = (const float*)d_in[0];
    const void*  ei = d_in[1];
    const float* W1 = (const float*)d_in[2];
    const float* b1 = (const float*)d_in[3];
    const float* W2 = (const float*)d_in[4];
    const float* b2 = (const float*)d_in[5];
    float* out = (float*)d_out;

    char* p = (char*)d_ws;
    size_t off = 0;
    auto alloc = [&](size_t bytes) {
        char* q = p + off;
        off = (off + bytes + 255) & ~(size_t)255;
        return q;
    };
    int*      flag = (int*)alloc(16);
    int*      deg  = (int*)alloc((size_t)N_NODES * 4);
    float*    dinv = (float*)alloc((size_t)N_NODES * 4);
    int*      cnt  = (int*)alloc((size_t)(N_NODES + 1) * 4);
    int*      offs = (int*)alloc((size_t)(N_NODES + 1) * 4);
    int*      bsum = (int*)alloc(512 * 4);
    int*      cur  = (int*)alloc((size_t)N_NODES * 4);
    int*      ccol = (int*)alloc((size_t)(N_EDGES + N_NODES) * 4);
    _Float16* h    = (_Float16*)alloc((size_t)N_NODES * CLS * 2);
    _Float16* s0   = (_Float16*)alloc((size_t)N_NODES * CLS * 2);
    _Float16* bufA = (_Float16*)alloc((size_t)N_NODES * CLS * 2);
    _Float16* bufB = (_Float16*)alloc((size_t)N_NODES * CLS * 2);
    _Float16* h1   = (_Float16*)alloc((size_t)N_NODES * HID * 2);
    _Float16* W1T  = (_Float16*)alloc((size_t)HID * FEAT * 2);
    _Float16* W2T  = (_Float16*)alloc((size_t)CLS * HID * 2);
    (void)ws_size;

    // graph build
    k_detect<<<1, 256, 0, stream>>>((const unsigned*)ei, flag);
    k_init<<<(N_NODES + 256) / 256, 256, 0, stream>>>(deg, cnt);
    k_hist<<<(N_EDGES + 255) / 256, 256, 0, stream>>>(ei, flag, deg, cnt);
    k_dinv<<<(N_NODES + 255) / 256, 256, 0, stream>>>(deg, dinv);
    const int nscan = N_NODES + 1;
    const int nblk = (nscan + 255) / 256;
    k_scan1<<<nblk, 256, 0, stream>>>(cnt, offs, bsum, nscan);
    k_scan2<<<1, 512, 0, stream>>>(bsum, nblk);
    k_scan3<<<nblk, 256, 0, stream>>>(offs, bsum, cur, nscan);
    k_scatter<<<(N_EDGES + N_NODES + 255) / 256, 256, 0, stream>>>(ei, flag, cur, ccol);

    // dense layers (fp16 MFMA)
    k_cvtW<<<512, 256, 0, stream>>>(W1, W2, W1T, W2T);
    k_gemm1<<<(N_NODES + 127) / 128, 512, 0, stream>>>(x, W1T, b1, h1, N_NODES);
    k_gemm2<<<(N_NODES + 255) / 256, 512, 0, stream>>>(h1, W2T, b2, dinv, h, s0, N_NODES);

    // K propagation steps; final step fuses log_softmax
    const int pgrid = (N_NODES + 3) / 4;
    _Float16* ping[2] = {bufA, bufB};
    for (int it = 0; it < K_ITER; it++) {
        const _Float16* src = (it == 0) ? s0 : ping[(it - 1) & 1];
        _Float16* dst = ping[it & 1];
        k_prop<<<pgrid, 256, 0, stream>>>(ccol, offs, dinv, src, h, dst, out, it == K_ITER - 1);
    }
}

// Round 4
// 1105.416 us; speedup vs baseline: 2.4750x; 1.5497x over previous
//
#include <hip/hip_runtime.h>
#include <hip/hip_bf16.h>
#include <math.h>

#define N_NODES 100000
#define N_EDGES 3200000
#define FEAT 512
#define HID 256
#define CLS 64
#define K_ITER 10
#define NBUCK 196            // ceil(100000 / 512) node buckets of width 512
#define BSH 9                // bucket = r >> 9

typedef _Float16 half8 __attribute__((ext_vector_type(8)));
typedef float f32x4 __attribute__((ext_vector_type(4)));

// ---------- edge index access (int32 or int64, detected at runtime) ----------
__device__ __forceinline__ int edge_at(const void* e, int is64, long long idx) {
    return is64 ? (int)((const long long*)e)[idx] : ((const int*)e)[idx];
}

__global__ void k_detect(const unsigned* __restrict__ e, int* __restrict__ flag) {
    __shared__ unsigned s[256];
    unsigned v = 0;
    for (int i = threadIdx.x; i < 4096; i += 256) v |= e[2 * i + 1];
    s[threadIdx.x] = v;
    __syncthreads();
    for (int off = 128; off; off >>= 1) {
        if (threadIdx.x < off) s[threadIdx.x] |= s[threadIdx.x + off];
        __syncthreads();
    }
    if (threadIdx.x == 0) flag[0] = (s[0] == 0) ? 1 : 0;
}

__global__ void k_init(int* __restrict__ deg, int* __restrict__ bcnt) {
    int i = blockIdx.x * 256 + threadIdx.x;
    if (i < N_NODES) deg[i] = 1;        // self loop
    if (i < NBUCK) bcnt[i] = 0;
}

// ---------- pass 0: bucket histogram + deg[c] ----------
#define EPB 8192
__global__ __launch_bounds__(256) void k_bcount(const void* __restrict__ e,
                                                const int* __restrict__ flag,
                                                int* __restrict__ deg,
                                                int* __restrict__ bcnt) {
    __shared__ int lh[NBUCK];
    for (int i = threadIdx.x; i < NBUCK; i += 256) lh[i] = 0;
    __syncthreads();
    int is64 = flag[0];
    long long base = (long long)blockIdx.x * EPB;
    for (int j = threadIdx.x; j < EPB; j += 256) {
        long long i = base + j;
        if (i < N_EDGES) {
            int r = edge_at(e, is64, i);
            int c = edge_at(e, is64, (long long)N_EDGES + i);
            atomicAdd(&lh[r >> BSH], 1);
            atomicAdd(&deg[c], 1);
        }
    }
    __syncthreads();
    for (int i = threadIdx.x; i < NBUCK; i += 256)
        if (lh[i]) atomicAdd(&bcnt[i], lh[i]);
}

__global__ void k_dinv(const int* __restrict__ deg, float* __restrict__ dinv) {
    int i = blockIdx.x * 256 + threadIdx.x;
    if (i < N_NODES) dinv[i] = rsqrtf((float)deg[i]);
}

// ---------- bucket base scan (196 entries; trivial serial) ----------
__global__ void k_bscan(const int* __restrict__ bcnt, int* __restrict__ bbase,
                        int* __restrict__ gcur, int* __restrict__ cbase,
                        int* __restrict__ offs) {
    if (threadIdx.x == 0) {
        int accE = 0, accC = 0;
        for (int b = 0; b < NBUCK; b++) {
            bbase[b] = accE;
            gcur[b] = accE;
            cbase[b] = accC;
            int nb0 = b << BSH;
            int nn = (N_NODES - nb0 < 512) ? (N_NODES - nb0) : 512;
            accE += bcnt[b];
            accC += bcnt[b] + nn;
        }
        bbase[NBUCK] = accE;
        cbase[NBUCK] = accC;
        offs[N_NODES] = accC;
    }
}

// ---------- pass A: bin edges into bucket-contiguous pair runs ----------
#define CH 4096
__global__ __launch_bounds__(256) void k_binA(const void* __restrict__ e,
                                              const int* __restrict__ flag,
                                              int* __restrict__ gcur,
                                              unsigned long long* __restrict__ pairs) {
    __shared__ int lh[NBUCK], gb[NBUCK], lc[NBUCK];
    for (int i = threadIdx.x; i < NBUCK; i += 256) lh[i] = 0;
    __syncthreads();
    int is64 = flag[0];
    long long base = (long long)blockIdx.x * CH;
    // phase 1: local histogram
    for (int j = threadIdx.x; j < CH; j += 256) {
        long long i = base + j;
        if (i < N_EDGES) {
            int r = edge_at(e, is64, i);
            atomicAdd(&lh[r >> BSH], 1);
        }
    }
    __syncthreads();
    // phase 2: reserve contiguous runs per bucket
    for (int i = threadIdx.x; i < NBUCK; i += 256) {
        lc[i] = 0;
        gb[i] = lh[i] ? atomicAdd(&gcur[i], lh[i]) : 0;
    }
    __syncthreads();
    // phase 3: place (re-read edges; L2-hot)
    for (int j = threadIdx.x; j < CH; j += 256) {
        long long i = base + j;
        if (i < N_EDGES) {
            int r = edge_at(e, is64, i);
            int c = edge_at(e, is64, (long long)N_EDGES + i);
            int b = r >> BSH;
            int pos = atomicAdd(&lc[b], 1);
            pairs[(long long)gb[b] + pos] =
                ((unsigned long long)(unsigned)c << 32) | (unsigned)r;
        }
    }
}

// ---------- pass B: per-bucket CSR build (one block per bucket) ----------
__global__ __launch_bounds__(1024) void k_binB(const unsigned long long* __restrict__ pairs,
                                               const int* __restrict__ bbase,
                                               const int* __restrict__ cbase,
                                               int* __restrict__ offs,
                                               int* __restrict__ ccol) {
    __shared__ int cnt[512], cur[512], s[512];
    const int b = blockIdx.x;
    const int nb0 = b << BSH;
    const int nn = (N_NODES - nb0 < 512) ? (N_NODES - nb0) : 512;
    const int t = threadIdx.x;
    if (t < 512) cnt[t] = (t < nn) ? 1 : 0;  // self loop
    __syncthreads();
    const int e0 = bbase[b], e1 = bbase[b + 1];
    for (int i = e0 + t; i < e1; i += 1024) {
        int r = (int)(pairs[i] & 0xffffffffu);
        atomicAdd(&cnt[r - nb0], 1);
    }
    __syncthreads();
    // exclusive scan of cnt[0..511]
    int v = (t < 512) ? cnt[t] : 0;
    if (t < 512) s[t] = v;
    __syncthreads();
    for (int off = 1; off < 512; off <<= 1) {
        int a = 0;
        if (t < 512 && t >= off) a = s[t - off];
        __syncthreads();
        if (t < 512) s[t] += a;
        __syncthreads();
    }
    const int cb = cbase[b];
    if (t < 512) {
        int excl = s[t] - v;
        cur[t] = excl;
        if (t < nn) {
            offs[nb0 + t] = cb + excl;
            ccol[cb + excl] = nb0 + t;  // self loop entry
            cur[t] = excl + 1;
        }
    }
    __syncthreads();
    for (int i = e0 + t; i < e1; i += 1024) {
        unsigned long long p = pairs[i];
        int r = (int)(p & 0xffffffffu);
        int c = (int)(p >> 32);
        int pos = atomicAdd(&cur[r - nb0], 1);
        ccol[cb + pos] = c;
    }
}

// ---------- weight transpose + fp16 convert ----------
__global__ void k_cvtW(const float* __restrict__ W1, const float* __restrict__ W2,
                       _Float16* __restrict__ W1T, _Float16* __restrict__ W2T) {
    int i = blockIdx.x * 256 + threadIdx.x;
    if (i < 256 * 512) {
        int n = i >> 9, k = i & 511;
        W1T[i] = (_Float16)W1[k * 256 + n];
    }
    if (i < 64 * 256) {
        int n = i >> 8, k = i & 255;
        W2T[i] = (_Float16)W2[k * 64 + n];
    }
}

// swizzle helper: physical granule for (row, logical granule)
__device__ __forceinline__ int swz(int row, int g) {
    return g ^ (row & 3) ^ ((row >> 2) & 3);
}

// ---------- GEMM1: h1[M][256](fp16) = relu(x[M][512](fp32) @ W1 + b1) ----------
__global__ __launch_bounds__(512) void k_gemm1(const float* __restrict__ A,
                                               const _Float16* __restrict__ BT,
                                               const float* __restrict__ bias,
                                               _Float16* __restrict__ C, int M) {
    __shared__ __align__(16) char lds[8192 + 16384];
    const int t = threadIdx.x;
    const int wid = t >> 6, lane = t & 63;
    const int wr = wid >> 2, wc = wid & 3;
    const int srow = t >> 2, sg = t & 3;
    const int fr = lane & 15, fg = lane >> 4;
    const long long by = blockIdx.x;

    f32x4 acc[4][4] = {};
    const long long arow = by * 128 + srow;
    const bool avalid = (arow < M);
    const float* ap0 = A + arow * FEAT + sg * 8;

    for (int kt = 0; kt < FEAT; kt += 32) {
        float4 a0 = make_float4(0.f, 0.f, 0.f, 0.f), a1 = a0;
        if (avalid) {
            const float* ap = ap0 + kt;
            a0 = *(const float4*)ap;
            a1 = *(const float4*)(ap + 4);
        }
        half8 ah;
        ah[0] = (_Float16)a0.x; ah[1] = (_Float16)a0.y;
        ah[2] = (_Float16)a0.z; ah[3] = (_Float16)a0.w;
        ah[4] = (_Float16)a1.x; ah[5] = (_Float16)a1.y;
        ah[6] = (_Float16)a1.z; ah[7] = (_Float16)a1.w;
        *(half8*)(lds + srow * 64 + swz(srow, sg) * 16) = ah;
#pragma unroll
        for (int rep = 0; rep < 2; rep++) {
            int brow = rep * 128 + srow;
            half8 bh = *(const half8*)(BT + brow * FEAT + kt + sg * 8);
            *(half8*)(lds + 8192 + brow * 64 + swz(brow, sg) * 16) = bh;
        }
        __syncthreads();

        half8 af[4], bf[4];
#pragma unroll
        for (int mi = 0; mi < 4; mi++) {
            int r = wr * 64 + mi * 16 + fr;
            af[mi] = *(const half8*)(lds + r * 64 + swz(r, fg) * 16);
        }
#pragma unroll
        for (int nj = 0; nj < 4; nj++) {
            int r = wc * 64 + nj * 16 + fr;
            bf[nj] = *(const half8*)(lds + 8192 + r * 64 + swz(r, fg) * 16);
        }
#pragma unroll
        for (int mi = 0; mi < 4; mi++)
#pragma unroll
            for (int nj = 0; nj < 4; nj++)
                acc[mi][nj] = __builtin_amdgcn_mfma_f32_16x16x32_f16(af[mi], bf[nj], acc[mi][nj], 0, 0, 0);
        __syncthreads();
    }

#pragma unroll
    for (int mi = 0; mi < 4; mi++) {
#pragma unroll
        for (int nj = 0; nj < 4; nj++) {
            int col = wc * 64 + nj * 16 + fr;
            float bv = bias[col];
#pragma unroll
            for (int r = 0; r < 4; r++) {
                long long row = by * 128 + wr * 64 + mi * 16 + fg * 4 + r;
                if (row < M) {
                    float v = fmaxf(acc[mi][nj][r] + bv, 0.f);
                    C[row * HID + col] = (_Float16)v;
                }
            }
        }
    }
}

// ---------- GEMM2: h[M][64](fp16), s0[M][64](fp16 = dinv*h) ----------
__global__ __launch_bounds__(512) void k_gemm2(const _Float16* __restrict__ A,
                                               const _Float16* __restrict__ BT,
                                               const float* __restrict__ bias,
                                               const float* __restrict__ dinv,
                                               _Float16* __restrict__ Hout,
                                               _Float16* __restrict__ S0, int M) {
    __shared__ __align__(16) char lds[16384 + 4096];
    const int t = threadIdx.x;
    const int wid = t >> 6, lane = t & 63;
    const int wr = wid >> 1, wc = wid & 1;
    const int srow = t >> 2, sg = t & 3;
    const int fr = lane & 15, fg = lane >> 4;
    const long long bm = blockIdx.x;

    f32x4 acc[4][2] = {};

    for (int kt = 0; kt < HID; kt += 32) {
#pragma unroll
        for (int rep = 0; rep < 2; rep++) {
            int ar = rep * 128 + srow;
            long long grow = bm * 256 + ar;
            if (grow >= M) grow = M - 1;
            half8 ah = *(const half8*)(A + grow * HID + kt + sg * 8);
            *(half8*)(lds + ar * 64 + swz(ar, sg) * 16) = ah;
        }
        if (t < 256) {
            int br = t >> 2;
            half8 bh = *(const half8*)(BT + br * HID + kt + sg * 8);
            *(half8*)(lds + 16384 + br * 64 + swz(br, sg) * 16) = bh;
        }
        __syncthreads();

        half8 af[4], bf[2];
#pragma unroll
        for (int mi = 0; mi < 4; mi++) {
            int r = wr * 64 + mi * 16 + fr;
            af[mi] = *(const half8*)(lds + r * 64 + swz(r, fg) * 16);
        }
#pragma unroll
        for (int nj = 0; nj < 2; nj++) {
            int r = wc * 32 + nj * 16 + fr;
            bf[nj] = *(const half8*)(lds + 16384 + r * 64 + swz(r, fg) * 16);
        }
#pragma unroll
        for (int mi = 0; mi < 4; mi++)
#pragma unroll
            for (int nj = 0; nj < 2; nj++)
                acc[mi][nj] = __builtin_amdgcn_mfma_f32_16x16x32_f16(af[mi], bf[nj], acc[mi][nj], 0, 0, 0);
        __syncthreads();
    }

#pragma unroll
    for (int mi = 0; mi < 4; mi++) {
#pragma unroll
        for (int nj = 0; nj < 2; nj++) {
            int col = wc * 32 + nj * 16 + fr;
            float bv = bias[col];
#pragma unroll
            for (int r = 0; r < 4; r++) {
                long long row = bm * 256 + wr * 64 + mi * 16 + fg * 4 + r;
                if (row < M) {
                    float o = acc[mi][nj][r] + bv;
                    Hout[row * CLS + col] = (_Float16)o;
                    S0[row * CLS + col] = (_Float16)(dinv[row] * o);
                }
            }
        }
    }
}

// ---------- propagation: one wave per node, lane = class, 8-deep MLP ----------
__global__ __launch_bounds__(256) void k_prop(const int* __restrict__ ccol,
                                              const int* __restrict__ offs,
                                              const float* __restrict__ dinv,
                                              const _Float16* __restrict__ src,
                                              const _Float16* __restrict__ h,
                                              _Float16* __restrict__ dst,
                                              float* __restrict__ out, int last) {
    int wid = (blockIdx.x << 2) + (threadIdx.x >> 6);
    int lane = threadIdx.x & 63;
    if (wid >= N_NODES) return;
    int e0 = offs[wid], e1 = offs[wid + 1];
    float acc = 0.f;
    int e = e0;
    for (; e + 8 <= e1; e += 8) {
        int cc[8];
#pragma unroll
        for (int u = 0; u < 8; u++) cc[u] = ccol[e + u];
        float vv[8];
#pragma unroll
        for (int u = 0; u < 8; u++)
            vv[u] = (float)src[(long long)cc[u] * CLS + lane];
#pragma unroll
        for (int u = 0; u < 8; u++) acc += vv[u];
    }
    if (e + 4 <= e1) {
        int cc[4];
#pragma unroll
        for (int u = 0; u < 4; u++) cc[u] = ccol[e + u];
#pragma unroll
        for (int u = 0; u < 4; u++)
            acc += (float)src[(long long)cc[u] * CLS + lane];
        e += 4;
    }
    for (; e < e1; e++) acc += (float)src[(long long)ccol[e] * CLS + lane];

    float dr = dinv[wid];
    float o = 0.9f * dr * acc + 0.1f * (float)h[(long long)wid * CLS + lane];
    if (!last) {
        dst[(long long)wid * CLS + lane] = (_Float16)(dr * o);
    } else {
        float m = o;
        for (int off = 32; off; off >>= 1) m = fmaxf(m, __shfl_xor(m, off));
        float s = expf(o - m);
        for (int off = 32; off; off >>= 1) s += __shfl_xor(s, off);
        out[(long long)wid * CLS + lane] = o - m - logf(s);
    }
}

extern "C" void kernel_launch(void* const* d_in, const int* in_sizes, int n_in,
                              void* d_out, int out_size, void* d_ws, size_t ws_size,
                              hipStream_t stream) {
    const float* x  = (const float*)d_in[0];
    const void*  ei = d_in[1];
    const float* W1 = (const float*)d_in[2];
    const float* b1 = (const float*)d_in[3];
    const float* W2 = (const float*)d_in[4];
    const float* b2 = (const float*)d_in[5];
    float* out = (float*)d_out;

    char* p = (char*)d_ws;
    size_t off = 0;
    auto alloc = [&](size_t bytes) {
        char* q = p + off;
        off = (off + bytes + 255) & ~(size_t)255;
        return q;
    };
    int*      flag  = (int*)alloc(16);
    int*      deg   = (int*)alloc((size_t)N_NODES * 4);
    float*    dinv  = (float*)alloc((size_t)N_NODES * 4);
    int*      offs  = (int*)alloc((size_t)(N_NODES + 1) * 4);
    int*      bcnt  = (int*)alloc((NBUCK + 1) * 4);
    int*      bbase = (int*)alloc((NBUCK + 1) * 4);
    int*      cbase = (int*)alloc((NBUCK + 1) * 4);
    int*      gcur  = (int*)alloc((NBUCK + 1) * 4);
    unsigned long long* pairs = (unsigned long long*)alloc((size_t)N_EDGES * 8);
    int*      ccol  = (int*)alloc((size_t)(N_EDGES + N_NODES) * 4);
    _Float16* h     = (_Float16*)alloc((size_t)N_NODES * CLS * 2);
    _Float16* s0    = (_Float16*)alloc((size_t)N_NODES * CLS * 2);
    _Float16* bufA  = (_Float16*)alloc((size_t)N_NODES * CLS * 2);
    _Float16* bufB  = (_Float16*)alloc((size_t)N_NODES * CLS * 2);
    _Float16* h1    = (_Float16*)alloc((size_t)N_NODES * HID * 2);
    _Float16* W1T   = (_Float16*)alloc((size_t)HID * FEAT * 2);
    _Float16* W2T   = (_Float16*)alloc((size_t)CLS * HID * 2);
    (void)ws_size;

    // graph build
    k_detect<<<1, 256, 0, stream>>>((const unsigned*)ei, flag);
    k_init<<<(N_NODES + 255) / 256, 256, 0, stream>>>(deg, bcnt);
    k_bcount<<<(N_EDGES + EPB - 1) / EPB, 256, 0, stream>>>(ei, flag, deg, bcnt);
    k_dinv<<<(N_NODES + 255) / 256, 256, 0, stream>>>(deg, dinv);
    k_bscan<<<1, 64, 0, stream>>>(bcnt, bbase, gcur, cbase, offs);
    k_binA<<<(N_EDGES + CH - 1) / CH, 256, 0, stream>>>(ei, flag, gcur, pairs);
    k_binB<<<NBUCK, 1024, 0, stream>>>(pairs, bbase, cbase, offs, ccol);

    // dense layers (fp16 MFMA)
    k_cvtW<<<512, 256, 0, stream>>>(W1, W2, W1T, W2T);
    k_gemm1<<<(N_NODES + 127) / 128, 512, 0, stream>>>(x, W1T, b1, h1, N_NODES);
    k_gemm2<<<(N_NODES + 255) / 256, 512, 0, stream>>>(h1, W2T, b2, dinv, h, s0, N_NODES);

    // K propagation steps; final step fuses log_softmax
    const int pgrid = (N_NODES + 3) / 4;
    _Float16* ping[2] = {bufA, bufB};
    for (int it = 0; it < K_ITER; it++) {
        const _Float16* src = (it == 0) ? s0 : ping[(it - 1) & 1];
        _Float16* dst = ping[it & 1];
        k_prop<<<pgrid, 256, 0, stream>>>(ccol, offs, dinv, src, h, dst, out, it == K_ITER - 1);
    }
}

// Round 5
// 966.363 us; speedup vs baseline: 2.8312x; 1.1439x over previous
//
#include <hip/hip_runtime.h>
#include <hip/hip_bf16.h>
#include <math.h>

#define N_NODES 100000
#define N_EDGES 3200000
#define FEAT 512
#define HID 256
#define CLS 64
#define K_ITER 10
#define NBUCK 196            // ceil(100000 / 512) node buckets of width 512
#define BSH 9                // bucket = r >> 9

typedef _Float16 half8 __attribute__((ext_vector_type(8)));
typedef _Float16 half4v __attribute__((ext_vector_type(4)));
typedef float f32x4 __attribute__((ext_vector_type(4)));

// ---------- edge index access (int32 or int64, detected at runtime) ----------
__device__ __forceinline__ int edge_at(const void* e, int is64, long long idx) {
    return is64 ? (int)((const long long*)e)[idx] : ((const int*)e)[idx];
}

__global__ void k_detect(const unsigned* __restrict__ e, int* __restrict__ flag) {
    __shared__ unsigned s[256];
    unsigned v = 0;
    for (int i = threadIdx.x; i < 4096; i += 256) v |= e[2 * i + 1];
    s[threadIdx.x] = v;
    __syncthreads();
    for (int off = 128; off; off >>= 1) {
        if (threadIdx.x < off) s[threadIdx.x] |= s[threadIdx.x + off];
        __syncthreads();
    }
    if (threadIdx.x == 0) flag[0] = (s[0] == 0) ? 1 : 0;
}

__global__ void k_init(int* __restrict__ bcntR, int* __restrict__ bcntC) {
    for (int i = threadIdx.x; i < NBUCK; i += 256) { bcntR[i] = 0; bcntC[i] = 0; }
}

// ---------- pass 0: dual bucket histogram (r and c), no value atomics ----------
#define CHB 4096
__global__ __launch_bounds__(256) void k_bhist(const void* __restrict__ e,
                                               const int* __restrict__ flag,
                                               int* __restrict__ bcntR,
                                               int* __restrict__ bcntC) {
    __shared__ int lhR[NBUCK], lhC[NBUCK];
    for (int i = threadIdx.x; i < NBUCK; i += 256) { lhR[i] = 0; lhC[i] = 0; }
    __syncthreads();
    int is64 = flag[0];
    long long base = (long long)blockIdx.x * CHB;
    for (int j = threadIdx.x; j < CHB; j += 256) {
        long long i = base + j;
        if (i < N_EDGES) {
            int r = edge_at(e, is64, i);
            int c = edge_at(e, is64, (long long)N_EDGES + i);
            atomicAdd(&lhR[r >> BSH], 1);
            atomicAdd(&lhC[c >> BSH], 1);
        }
    }
    __syncthreads();
    for (int i = threadIdx.x; i < NBUCK; i += 256) {
        if (lhR[i]) atomicAdd(&bcntR[i], lhR[i]);
        if (lhC[i]) atomicAdd(&bcntC[i], lhC[i]);
    }
}

// ---------- bucket base scan (196 entries; trivial serial) ----------
__global__ void k_bscan(const int* __restrict__ bcntR, const int* __restrict__ bcntC,
                        int* __restrict__ bbaseR, int* __restrict__ gcurR,
                        int* __restrict__ bbaseC, int* __restrict__ gcurC,
                        int* __restrict__ cbase, int* __restrict__ offs) {
    if (threadIdx.x == 0) {
        int accE = 0, accC = 0, accCv = 0;
        for (int b = 0; b < NBUCK; b++) {
            bbaseR[b] = accE;
            gcurR[b] = accE;
            bbaseC[b] = accCv;
            gcurC[b] = accCv;
            cbase[b] = accC;
            int nb0 = b << BSH;
            int nn = (N_NODES - nb0 < 512) ? (N_NODES - nb0) : 512;
            accE += bcntR[b];
            accCv += bcntC[b];
            accC += bcntR[b] + nn;
        }
        bbaseR[NBUCK] = accE;
        bbaseC[NBUCK] = accCv;
        cbase[NBUCK] = accC;
        offs[N_NODES] = accC;
    }
}

// ---------- pass A: bin edges into bucket-contiguous runs (r-pairs and c-vals) ----------
#define CH 4096
__global__ __launch_bounds__(256) void k_binA(const void* __restrict__ e,
                                              const int* __restrict__ flag,
                                              int* __restrict__ gcurR,
                                              int* __restrict__ gcurC,
                                              unsigned long long* __restrict__ pairs,
                                              int* __restrict__ cvals) {
    __shared__ int lhR[NBUCK], gbR[NBUCK], lcR[NBUCK];
    __shared__ int lhC[NBUCK], gbC[NBUCK], lcC[NBUCK];
    for (int i = threadIdx.x; i < NBUCK; i += 256) { lhR[i] = 0; lhC[i] = 0; }
    __syncthreads();
    int is64 = flag[0];
    long long base = (long long)blockIdx.x * CH;
    // phase 1: local histograms
    for (int j = threadIdx.x; j < CH; j += 256) {
        long long i = base + j;
        if (i < N_EDGES) {
            int r = edge_at(e, is64, i);
            int c = edge_at(e, is64, (long long)N_EDGES + i);
            atomicAdd(&lhR[r >> BSH], 1);
            atomicAdd(&lhC[c >> BSH], 1);
        }
    }
    __syncthreads();
    // phase 2: reserve contiguous runs per bucket
    for (int i = threadIdx.x; i < NBUCK; i += 256) {
        lcR[i] = 0;
        lcC[i] = 0;
        gbR[i] = lhR[i] ? atomicAdd(&gcurR[i], lhR[i]) : 0;
        gbC[i] = lhC[i] ? atomicAdd(&gcurC[i], lhC[i]) : 0;
    }
    __syncthreads();
    // phase 3: place (re-read edges; L2-hot)
    for (int j = threadIdx.x; j < CH; j += 256) {
        long long i = base + j;
        if (i < N_EDGES) {
            int r = edge_at(e, is64, i);
            int c = edge_at(e, is64, (long long)N_EDGES + i);
            int b = r >> BSH;
            int pos = atomicAdd(&lcR[b], 1);
            pairs[(long long)gbR[b] + pos] =
                ((unsigned long long)(unsigned)c << 32) | (unsigned)r;
            int bc = c >> BSH;
            int posc = atomicAdd(&lcC[bc], 1);
            cvals[(long long)gbC[bc] + posc] = c;
        }
    }
}

// ---------- deg/dinv: per-bucket LDS count of c occurrences ----------
__global__ __launch_bounds__(1024) void k_degB(const int* __restrict__ cvals,
                                               const int* __restrict__ bbaseC,
                                               float* __restrict__ dinv) {
    __shared__ int cnt[512];
    const int b = blockIdx.x;
    const int nb0 = b << BSH;
    const int nn = (N_NODES - nb0 < 512) ? (N_NODES - nb0) : 512;
    const int t = threadIdx.x;
    if (t < 512) cnt[t] = 1;  // self loop
    __syncthreads();
    const int e0 = bbaseC[b], e1 = bbaseC[b + 1];
    for (int i = e0 + t; i < e1; i += 1024) {
        atomicAdd(&cnt[cvals[i] - nb0], 1);
    }
    __syncthreads();
    if (t < nn) dinv[nb0 + t] = rsqrtf((float)cnt[t]);
}

// ---------- pass B: per-bucket CSR build (one block per bucket) ----------
__global__ __launch_bounds__(1024) void k_binB(const unsigned long long* __restrict__ pairs,
                                               const int* __restrict__ bbaseR,
                                               const int* __restrict__ cbase,
                                               int* __restrict__ offs,
                                               int* __restrict__ ccol) {
    __shared__ int cnt[512], cur[512], s[512];
    const int b = blockIdx.x;
    const int nb0 = b << BSH;
    const int nn = (N_NODES - nb0 < 512) ? (N_NODES - nb0) : 512;
    const int t = threadIdx.x;
    if (t < 512) cnt[t] = (t < nn) ? 1 : 0;  // self loop
    __syncthreads();
    const int e0 = bbaseR[b], e1 = bbaseR[b + 1];
    for (int i = e0 + t; i < e1; i += 1024) {
        int r = (int)(pairs[i] & 0xffffffffu);
        atomicAdd(&cnt[r - nb0], 1);
    }
    __syncthreads();
    // exclusive scan of cnt[0..511]
    int v = (t < 512) ? cnt[t] : 0;
    if (t < 512) s[t] = v;
    __syncthreads();
    for (int off = 1; off < 512; off <<= 1) {
        int a = 0;
        if (t < 512 && t >= off) a = s[t - off];
        __syncthreads();
        if (t < 512) s[t] += a;
        __syncthreads();
    }
    const int cb = cbase[b];
    if (t < 512) {
        int excl = s[t] - v;
        cur[t] = excl;
        if (t < nn) {
            offs[nb0 + t] = cb + excl;
            ccol[cb + excl] = nb0 + t;  // self loop entry
            cur[t] = excl + 1;
        }
    }
    __syncthreads();
    for (int i = e0 + t; i < e1; i += 1024) {
        unsigned long long p = pairs[i];
        int r = (int)(p & 0xffffffffu);
        int c = (int)(p >> 32);
        int pos = atomicAdd(&cur[r - nb0], 1);
        ccol[cb + pos] = c;
    }
}

// ---------- weight transpose + fp16 convert ----------
__global__ void k_cvtW(const float* __restrict__ W1, const float* __restrict__ W2,
                       _Float16* __restrict__ W1T, _Float16* __restrict__ W2T) {
    int i = blockIdx.x * 256 + threadIdx.x;
    if (i < 256 * 512) {
        int n = i >> 9, k = i & 511;
        W1T[i] = (_Float16)W1[k * 256 + n];
    }
    if (i < 64 * 256) {
        int n = i >> 8, k = i & 255;
        W2T[i] = (_Float16)W2[k * 64 + n];
    }
}

// swizzle helper: physical granule for (row, logical granule)
__device__ __forceinline__ int swz(int row, int g) {
    return g ^ (row & 3) ^ ((row >> 2) & 3);
}

// ---------- GEMM1: h1[M][256](fp16) = relu(x[M][512](fp32) @ W1 + b1) ----------
__global__ __launch_bounds__(512) void k_gemm1(const float* __restrict__ A,
                                               const _Float16* __restrict__ BT,
                                               const float* __restrict__ bias,
                                               _Float16* __restrict__ C, int M) {
    __shared__ __align__(16) char lds[8192 + 16384];
    const int t = threadIdx.x;
    const int wid = t >> 6, lane = t & 63;
    const int wr = wid >> 2, wc = wid & 3;
    const int srow = t >> 2, sg = t & 3;
    const int fr = lane & 15, fg = lane >> 4;
    const long long by = blockIdx.x;

    f32x4 acc[4][4] = {};
    const long long arow = by * 128 + srow;
    const bool avalid = (arow < M);
    const float* ap0 = A + arow * FEAT + sg * 8;

    for (int kt = 0; kt < FEAT; kt += 32) {
        float4 a0 = make_float4(0.f, 0.f, 0.f, 0.f), a1 = a0;
        if (avalid) {
            const float* ap = ap0 + kt;
            a0 = *(const float4*)ap;
            a1 = *(const float4*)(ap + 4);
        }
        half8 ah;
        ah[0] = (_Float16)a0.x; ah[1] = (_Float16)a0.y;
        ah[2] = (_Float16)a0.z; ah[3] = (_Float16)a0.w;
        ah[4] = (_Float16)a1.x; ah[5] = (_Float16)a1.y;
        ah[6] = (_Float16)a1.z; ah[7] = (_Float16)a1.w;
        *(half8*)(lds + srow * 64 + swz(srow, sg) * 16) = ah;
#pragma unroll
        for (int rep = 0; rep < 2; rep++) {
            int brow = rep * 128 + srow;
            half8 bh = *(const half8*)(BT + brow * FEAT + kt + sg * 8);
            *(half8*)(lds + 8192 + brow * 64 + swz(brow, sg) * 16) = bh;
        }
        __syncthreads();

        half8 af[4], bf[4];
#pragma unroll
        for (int mi = 0; mi < 4; mi++) {
            int r = wr * 64 + mi * 16 + fr;
            af[mi] = *(const half8*)(lds + r * 64 + swz(r, fg) * 16);
        }
#pragma unroll
        for (int nj = 0; nj < 4; nj++) {
            int r = wc * 64 + nj * 16 + fr;
            bf[nj] = *(const half8*)(lds + 8192 + r * 64 + swz(r, fg) * 16);
        }
#pragma unroll
        for (int mi = 0; mi < 4; mi++)
#pragma unroll
            for (int nj = 0; nj < 4; nj++)
                acc[mi][nj] = __builtin_amdgcn_mfma_f32_16x16x32_f16(af[mi], bf[nj], acc[mi][nj], 0, 0, 0);
        __syncthreads();
    }

#pragma unroll
    for (int mi = 0; mi < 4; mi++) {
#pragma unroll
        for (int nj = 0; nj < 4; nj++) {
            int col = wc * 64 + nj * 16 + fr;
            float bv = bias[col];
#pragma unroll
            for (int r = 0; r < 4; r++) {
                long long row = by * 128 + wr * 64 + mi * 16 + fg * 4 + r;
                if (row < M) {
                    float v = fmaxf(acc[mi][nj][r] + bv, 0.f);
                    C[row * HID + col] = (_Float16)v;
                }
            }
        }
    }
}

// ---------- GEMM2: h[M][64](fp16), s0[M][64](fp16 = dinv*h) ----------
__global__ __launch_bounds__(512) void k_gemm2(const _Float16* __restrict__ A,
                                               const _Float16* __restrict__ BT,
                                               const float* __restrict__ bias,
                                               const float* __restrict__ dinv,
                                               _Float16* __restrict__ Hout,
                                               _Float16* __restrict__ S0, int M) {
    __shared__ __align__(16) char lds[16384 + 4096];
    const int t = threadIdx.x;
    const int wid = t >> 6, lane = t & 63;
    const int wr = wid >> 1, wc = wid & 1;
    const int srow = t >> 2, sg = t & 3;
    const int fr = lane & 15, fg = lane >> 4;
    const long long bm = blockIdx.x;

    f32x4 acc[4][2] = {};

    for (int kt = 0; kt < HID; kt += 32) {
#pragma unroll
        for (int rep = 0; rep < 2; rep++) {
            int ar = rep * 128 + srow;
            long long grow = bm * 256 + ar;
            if (grow >= M) grow = M - 1;
            half8 ah = *(const half8*)(A + grow * HID + kt + sg * 8);
            *(half8*)(lds + ar * 64 + swz(ar, sg) * 16) = ah;
        }
        if (t < 256) {
            int br = t >> 2;
            half8 bh = *(const half8*)(BT + br * HID + kt + sg * 8);
            *(half8*)(lds + 16384 + br * 64 + swz(br, sg) * 16) = bh;
        }
        __syncthreads();

        half8 af[4], bf[2];
#pragma unroll
        for (int mi = 0; mi < 4; mi++) {
            int r = wr * 64 + mi * 16 + fr;
            af[mi] = *(const half8*)(lds + r * 64 + swz(r, fg) * 16);
        }
#pragma unroll
        for (int nj = 0; nj < 2; nj++) {
            int r = wc * 32 + nj * 16 + fr;
            bf[nj] = *(const half8*)(lds + 16384 + r * 64 + swz(r, fg) * 16);
        }
#pragma unroll
        for (int mi = 0; mi < 4; mi++)
#pragma unroll
            for (int nj = 0; nj < 2; nj++)
                acc[mi][nj] = __builtin_amdgcn_mfma_f32_16x16x32_f16(af[mi], bf[nj], acc[mi][nj], 0, 0, 0);
        __syncthreads();
    }

#pragma unroll
    for (int mi = 0; mi < 4; mi++) {
#pragma unroll
        for (int nj = 0; nj < 2; nj++) {
            int col = wc * 32 + nj * 16 + fr;
            float bv = bias[col];
#pragma unroll
            for (int r = 0; r < 4; r++) {
                long long row = bm * 256 + wr * 64 + mi * 16 + fg * 4 + r;
                if (row < M) {
                    float o = acc[mi][nj][r] + bv;
                    Hout[row * CLS + col] = (_Float16)o;
                    S0[row * CLS + col] = (_Float16)(dinv[row] * o);
                }
            }
        }
    }
}

// ---------- propagation: one wave per node; 4 edges per gather instruction ----------
// lane = (g = lane>>4 edge subgroup, sl = lane&15 class-quad). Each gather
// instruction pulls 4 random 128B rows (16 lanes x 8B each).
__global__ __launch_bounds__(256) void k_prop(const int* __restrict__ ccol,
                                              const int* __restrict__ offs,
                                              const float* __restrict__ dinv,
                                              const _Float16* __restrict__ src,
                                              const _Float16* __restrict__ h,
                                              _Float16* __restrict__ dst,
                                              float* __restrict__ out, int last) {
    int wid = (blockIdx.x << 2) + (threadIdx.x >> 6);
    int lane = threadIdx.x & 63;
    if (wid >= N_NODES) return;
    const int g = lane >> 4;
    const int sl = lane & 15;
    int e0 = offs[wid], e1 = offs[wid + 1];
    float a0 = 0.f, a1 = 0.f, a2 = 0.f, a3 = 0.f;
    int e = e0;
    for (; e + 8 <= e1; e += 8) {
        int c0 = ccol[e + g];
        int c1 = ccol[e + 4 + g];
        half4v v0 = *(const half4v*)(src + (long long)c0 * CLS + sl * 4);
        half4v v1 = *(const half4v*)(src + (long long)c1 * CLS + sl * 4);
        a0 += (float)v0[0]; a1 += (float)v0[1]; a2 += (float)v0[2]; a3 += (float)v0[3];
        a0 += (float)v1[0]; a1 += (float)v1[1]; a2 += (float)v1[2]; a3 += (float)v1[3];
    }
    for (; e < e1; e += 4) {
        int idx = e + g;
        if (idx < e1) {
            int c = ccol[idx];
            half4v v = *(const half4v*)(src + (long long)c * CLS + sl * 4);
            a0 += (float)v[0]; a1 += (float)v[1]; a2 += (float)v[2]; a3 += (float)v[3];
        }
    }
    // reduce across the 4 edge subgroups (lanes with same sl)
    a0 += __shfl_xor(a0, 16); a1 += __shfl_xor(a1, 16);
    a2 += __shfl_xor(a2, 16); a3 += __shfl_xor(a3, 16);
    a0 += __shfl_xor(a0, 32); a1 += __shfl_xor(a1, 32);
    a2 += __shfl_xor(a2, 32); a3 += __shfl_xor(a3, 32);

    float dr = dinv[wid];
    half4v hh = *(const half4v*)(h + (long long)wid * CLS + sl * 4);
    float o0 = 0.9f * dr * a0 + 0.1f * (float)hh[0];
    float o1 = 0.9f * dr * a1 + 0.1f * (float)hh[1];
    float o2 = 0.9f * dr * a2 + 0.1f * (float)hh[2];
    float o3 = 0.9f * dr * a3 + 0.1f * (float)hh[3];

    if (!last) {
        if (g == 0) {
            half4v ov;
            ov[0] = (_Float16)(dr * o0); ov[1] = (_Float16)(dr * o1);
            ov[2] = (_Float16)(dr * o2); ov[3] = (_Float16)(dr * o3);
            *(half4v*)(dst + (long long)wid * CLS + sl * 4) = ov;
        }
    } else {
        float m = fmaxf(fmaxf(o0, o1), fmaxf(o2, o3));
        for (int off = 1; off < 16; off <<= 1) m = fmaxf(m, __shfl_xor(m, off));
        float s = expf(o0 - m) + expf(o1 - m) + expf(o2 - m) + expf(o3 - m);
        for (int off = 1; off < 16; off <<= 1) s += __shfl_xor(s, off);
        float ls = logf(s);
        if (g == 0) {
            float4 ov = make_float4(o0 - m - ls, o1 - m - ls, o2 - m - ls, o3 - m - ls);
            *(float4*)(out + (long long)wid * CLS + sl * 4) = ov;
        }
    }
}

extern "C" void kernel_launch(void* const* d_in, const int* in_sizes, int n_in,
                              void* d_out, int out_size, void* d_ws, size_t ws_size,
                              hipStream_t stream) {
    const float* x  = (const float*)d_in[0];
    const void*  ei = d_in[1];
    const float* W1 = (const float*)d_in[2];
    const float* b1 = (const float*)d_in[3];
    const float* W2 = (const float*)d_in[4];
    const float* b2 = (const float*)d_in[5];
    float* out = (float*)d_out;

    char* p = (char*)d_ws;
    size_t off = 0;
    auto alloc = [&](size_t bytes) {
        char* q = p + off;
        off = (off + bytes + 255) & ~(size_t)255;
        return q;
    };
    int*      flag   = (int*)alloc(16);
    float*    dinv   = (float*)alloc((size_t)N_NODES * 4);
    int*      offs   = (int*)alloc((size_t)(N_NODES + 1) * 4);
    int*      bcntR  = (int*)alloc((NBUCK + 1) * 4);
    int*      bcntC  = (int*)alloc((NBUCK + 1) * 4);
    int*      bbaseR = (int*)alloc((NBUCK + 1) * 4);
    int*      bbaseC = (int*)alloc((NBUCK + 1) * 4);
    int*      cbase  = (int*)alloc((NBUCK + 1) * 4);
    int*      gcurR  = (int*)alloc((NBUCK + 1) * 4);
    int*      gcurC  = (int*)alloc((NBUCK + 1) * 4);
    unsigned long long* pairs = (unsigned long long*)alloc((size_t)N_EDGES * 8);
    int*      cvals  = (int*)alloc((size_t)N_EDGES * 4);
    int*      ccol   = (int*)alloc((size_t)(N_EDGES + N_NODES) * 4);
    _Float16* h      = (_Float16*)alloc((size_t)N_NODES * CLS * 2);
    _Float16* s0     = (_Float16*)alloc((size_t)N_NODES * CLS * 2);
    _Float16* bufA   = (_Float16*)alloc((size_t)N_NODES * CLS * 2);
    _Float16* bufB   = (_Float16*)alloc((size_t)N_NODES * CLS * 2);
    _Float16* h1     = (_Float16*)alloc((size_t)N_NODES * HID * 2);
    _Float16* W1T    = (_Float16*)alloc((size_t)HID * FEAT * 2);
    _Float16* W2T    = (_Float16*)alloc((size_t)CLS * HID * 2);
    (void)ws_size;

    // graph build
    k_detect<<<1, 256, 0, stream>>>((const unsigned*)ei, flag);
    k_init<<<1, 256, 0, stream>>>(bcntR, bcntC);
    k_bhist<<<(N_EDGES + CHB - 1) / CHB, 256, 0, stream>>>(ei, flag, bcntR, bcntC);
    k_bscan<<<1, 64, 0, stream>>>(bcntR, bcntC, bbaseR, gcurR, bbaseC, gcurC, cbase, offs);
    k_binA<<<(N_EDGES + CH - 1) / CH, 256, 0, stream>>>(ei, flag, gcurR, gcurC, pairs, cvals);
    k_degB<<<NBUCK, 1024, 0, stream>>>(cvals, bbaseC, dinv);
    k_binB<<<NBUCK, 1024, 0, stream>>>(pairs, bbaseR, cbase, offs, ccol);

    // dense layers (fp16 MFMA)
    k_cvtW<<<512, 256, 0, stream>>>(W1, W2, W1T, W2T);
    k_gemm1<<<(N_NODES + 127) / 128, 512, 0, stream>>>(x, W1T, b1, h1, N_NODES);
    k_gemm2<<<(N_NODES + 255) / 256, 512, 0, stream>>>(h1, W2T, b2, dinv, h, s0, N_NODES);

    // K propagation steps; final step fuses log_softmax
    const int pgrid = (N_NODES + 3) / 4;
    _Float16* ping[2] = {bufA, bufB};
    for (int it = 0; it < K_ITER; it++) {
        const _Float16* src = (it == 0) ? s0 : ping[(it - 1) & 1];
        _Float16* dst = ping[it & 1];
        k_prop<<<pgrid, 256, 0, stream>>>(ccol, offs, dinv, src, h, dst, out, it == K_ITER - 1);
    }
}

// Round 6
// 824.348 us; speedup vs baseline: 3.3189x; 1.1723x over previous
//
#include <hip/hip_runtime.h>
#include <hip/hip_bf16.h>
#include <math.h>

#define N_NODES 100000
#define N_EDGES 3200000
#define FEAT 512
#define HID 256
#define CLS 64
#define K_ITER 10
#define NBUCK 196            // ceil(100000 / 512) node buckets of width 512
#define BSH 9                // bucket = r >> 9

typedef _Float16 half8 __attribute__((ext_vector_type(8)));
typedef float f32x4 __attribute__((ext_vector_type(4)));

// ---------- edge index access (int32 or int64, detected at runtime) ----------
__device__ __forceinline__ int edge_at(const void* e, int is64, long long idx) {
    return is64 ? (int)((const long long*)e)[idx] : ((const int*)e)[idx];
}

__global__ void k_detect(const unsigned* __restrict__ e, int* __restrict__ flag) {
    __shared__ unsigned s[256];
    unsigned v = 0;
    for (int i = threadIdx.x; i < 4096; i += 256) v |= e[2 * i + 1];
    s[threadIdx.x] = v;
    __syncthreads();
    for (int off = 128; off; off >>= 1) {
        if (threadIdx.x < off) s[threadIdx.x] |= s[threadIdx.x + off];
        __syncthreads();
    }
    if (threadIdx.x == 0) flag[0] = (s[0] == 0) ? 1 : 0;
}

__global__ void k_init(int* __restrict__ bcntR, int* __restrict__ bcntC) {
    for (int i = threadIdx.x; i < NBUCK; i += 256) { bcntR[i] = 0; bcntC[i] = 0; }
}

// ---------- pass 0: dual bucket histogram (r and c), no value atomics ----------
#define CHB 4096
__global__ __launch_bounds__(256) void k_bhist(const void* __restrict__ e,
                                               const int* __restrict__ flag,
                                               int* __restrict__ bcntR,
                                               int* __restrict__ bcntC) {
    __shared__ int lhR[NBUCK], lhC[NBUCK];
    for (int i = threadIdx.x; i < NBUCK; i += 256) { lhR[i] = 0; lhC[i] = 0; }
    __syncthreads();
    int is64 = flag[0];
    long long base = (long long)blockIdx.x * CHB;
    for (int j = threadIdx.x; j < CHB; j += 256) {
        long long i = base + j;
        if (i < N_EDGES) {
            int r = edge_at(e, is64, i);
            int c = edge_at(e, is64, (long long)N_EDGES + i);
            atomicAdd(&lhR[r >> BSH], 1);
            atomicAdd(&lhC[c >> BSH], 1);
        }
    }
    __syncthreads();
    for (int i = threadIdx.x; i < NBUCK; i += 256) {
        if (lhR[i]) atomicAdd(&bcntR[i], lhR[i]);
        if (lhC[i]) atomicAdd(&bcntC[i], lhC[i]);
    }
}

// ---------- bucket base scan (196 entries; trivial serial) ----------
__global__ void k_bscan(const int* __restrict__ bcntR, const int* __restrict__ bcntC,
                        int* __restrict__ bbaseR, int* __restrict__ gcurR,
                        int* __restrict__ bbaseC, int* __restrict__ gcurC,
                        int* __restrict__ cbase, int* __restrict__ offs) {
    if (threadIdx.x == 0) {
        int accE = 0, accC = 0, accCv = 0;
        for (int b = 0; b < NBUCK; b++) {
            bbaseR[b] = accE;
            gcurR[b] = accE;
            bbaseC[b] = accCv;
            gcurC[b] = accCv;
            cbase[b] = accC;
            int nb0 = b << BSH;
            int nn = (N_NODES - nb0 < 512) ? (N_NODES - nb0) : 512;
            accE += bcntR[b];
            accCv += bcntC[b];
            accC += bcntR[b] + nn;
        }
        bbaseR[NBUCK] = accE;
        bbaseC[NBUCK] = accCv;
        cbase[NBUCK] = accC;
        offs[N_NODES] = accC;
    }
}

// ---------- pass A: bin edges into bucket-contiguous runs (r-pairs and c-vals) ----------
#define CH 4096
__global__ __launch_bounds__(256) void k_binA(const void* __restrict__ e,
                                              const int* __restrict__ flag,
                                              int* __restrict__ gcurR,
                                              int* __restrict__ gcurC,
                                              unsigned long long* __restrict__ pairs,
                                              int* __restrict__ cvals) {
    __shared__ int lhR[NBUCK], gbR[NBUCK], lcR[NBUCK];
    __shared__ int lhC[NBUCK], gbC[NBUCK], lcC[NBUCK];
    for (int i = threadIdx.x; i < NBUCK; i += 256) { lhR[i] = 0; lhC[i] = 0; }
    __syncthreads();
    int is64 = flag[0];
    long long base = (long long)blockIdx.x * CH;
    // phase 1: local histograms
    for (int j = threadIdx.x; j < CH; j += 256) {
        long long i = base + j;
        if (i < N_EDGES) {
            int r = edge_at(e, is64, i);
            int c = edge_at(e, is64, (long long)N_EDGES + i);
            atomicAdd(&lhR[r >> BSH], 1);
            atomicAdd(&lhC[c >> BSH], 1);
        }
    }
    __syncthreads();
    // phase 2: reserve contiguous runs per bucket
    for (int i = threadIdx.x; i < NBUCK; i += 256) {
        lcR[i] = 0;
        lcC[i] = 0;
        gbR[i] = lhR[i] ? atomicAdd(&gcurR[i], lhR[i]) : 0;
        gbC[i] = lhC[i] ? atomicAdd(&gcurC[i], lhC[i]) : 0;
    }
    __syncthreads();
    // phase 3: place (re-read edges; L2-hot)
    for (int j = threadIdx.x; j < CH; j += 256) {
        long long i = base + j;
        if (i < N_EDGES) {
            int r = edge_at(e, is64, i);
            int c = edge_at(e, is64, (long long)N_EDGES + i);
            int b = r >> BSH;
            int pos = atomicAdd(&lcR[b], 1);
            pairs[(long long)gbR[b] + pos] =
                ((unsigned long long)(unsigned)c << 32) | (unsigned)r;
            int bc = c >> BSH;
            int posc = atomicAdd(&lcC[bc], 1);
            cvals[(long long)gbC[bc] + posc] = c;
        }
    }
}

// ---------- deg/dinv: per-bucket LDS count of c occurrences ----------
__global__ __launch_bounds__(1024) void k_degB(const int* __restrict__ cvals,
                                               const int* __restrict__ bbaseC,
                                               float* __restrict__ dinv) {
    __shared__ int cnt[512];
    const int b = blockIdx.x;
    const int nb0 = b << BSH;
    const int nn = (N_NODES - nb0 < 512) ? (N_NODES - nb0) : 512;
    const int t = threadIdx.x;
    if (t < 512) cnt[t] = 1;  // self loop
    __syncthreads();
    const int e0 = bbaseC[b], e1 = bbaseC[b + 1];
    for (int i = e0 + t; i < e1; i += 1024) {
        atomicAdd(&cnt[cvals[i] - nb0], 1);
    }
    __syncthreads();
    if (t < nn) dinv[nb0 + t] = rsqrtf((float)cnt[t]);
}

// ---------- pass B: per-bucket CSR build (one block per bucket) ----------
__global__ __launch_bounds__(1024) void k_binB(const unsigned long long* __restrict__ pairs,
                                               const int* __restrict__ bbaseR,
                                               const int* __restrict__ cbase,
                                               int* __restrict__ offs,
                                               int* __restrict__ ccol) {
    __shared__ int cnt[512], cur[512], s[512];
    const int b = blockIdx.x;
    const int nb0 = b << BSH;
    const int nn = (N_NODES - nb0 < 512) ? (N_NODES - nb0) : 512;
    const int t = threadIdx.x;
    if (t < 512) cnt[t] = (t < nn) ? 1 : 0;  // self loop
    __syncthreads();
    const int e0 = bbaseR[b], e1 = bbaseR[b + 1];
    for (int i = e0 + t; i < e1; i += 1024) {
        int r = (int)(pairs[i] & 0xffffffffu);
        atomicAdd(&cnt[r - nb0], 1);
    }
    __syncthreads();
    // exclusive scan of cnt[0..511]
    int v = (t < 512) ? cnt[t] : 0;
    if (t < 512) s[t] = v;
    __syncthreads();
    for (int off = 1; off < 512; off <<= 1) {
        int a = 0;
        if (t < 512 && t >= off) a = s[t - off];
        __syncthreads();
        if (t < 512) s[t] += a;
        __syncthreads();
    }
    const int cb = cbase[b];
    if (t < 512) {
        int excl = s[t] - v;
        cur[t] = excl;
        if (t < nn) {
            offs[nb0 + t] = cb + excl;
            ccol[cb + excl] = nb0 + t;  // self loop entry
            cur[t] = excl + 1;
        }
    }
    __syncthreads();
    for (int i = e0 + t; i < e1; i += 1024) {
        unsigned long long p = pairs[i];
        int r = (int)(p & 0xffffffffu);
        int c = (int)(p >> 32);
        int pos = atomicAdd(&cur[r - nb0], 1);
        ccol[cb + pos] = c;
    }
}

// ---------- weight transpose + fp16 convert ----------
__global__ void k_cvtW(const float* __restrict__ W1, const float* __restrict__ W2,
                       _Float16* __restrict__ W1T, _Float16* __restrict__ W2T) {
    int i = blockIdx.x * 256 + threadIdx.x;
    if (i < 256 * 512) {
        int n = i >> 9, k = i & 511;
        W1T[i] = (_Float16)W1[k * 256 + n];
    }
    if (i < 64 * 256) {
        int n = i >> 8, k = i & 255;
        W2T[i] = (_Float16)W2[k * 64 + n];
    }
}

// swizzle helper: physical granule for (row, logical granule)
__device__ __forceinline__ int swz(int row, int g) {
    return g ^ (row & 3) ^ ((row >> 2) & 3);
}

// ---------- GEMM1: h1[M][256](fp16) = relu(x[M][512](fp32) @ W1 + b1) ----------
__global__ __launch_bounds__(512) void k_gemm1(const float* __restrict__ A,
                                               const _Float16* __restrict__ BT,
                                               const float* __restrict__ bias,
                                               _Float16* __restrict__ C, int M) {
    __shared__ __align__(16) char lds[8192 + 16384];
    const int t = threadIdx.x;
    const int wid = t >> 6, lane = t & 63;
    const int wr = wid >> 2, wc = wid & 3;
    const int srow = t >> 2, sg = t & 3;
    const int fr = lane & 15, fg = lane >> 4;
    const long long by = blockIdx.x;

    f32x4 acc[4][4] = {};
    const long long arow = by * 128 + srow;
    const bool avalid = (arow < M);
    const float* ap0 = A + arow * FEAT + sg * 8;

    for (int kt = 0; kt < FEAT; kt += 32) {
        float4 a0 = make_float4(0.f, 0.f, 0.f, 0.f), a1 = a0;
        if (avalid) {
            const float* ap = ap0 + kt;
            a0 = *(const float4*)ap;
            a1 = *(const float4*)(ap + 4);
        }
        half8 ah;
        ah[0] = (_Float16)a0.x; ah[1] = (_Float16)a0.y;
        ah[2] = (_Float16)a0.z; ah[3] = (_Float16)a0.w;
        ah[4] = (_Float16)a1.x; ah[5] = (_Float16)a1.y;
        ah[6] = (_Float16)a1.z; ah[7] = (_Float16)a1.w;
        *(half8*)(lds + srow * 64 + swz(srow, sg) * 16) = ah;
#pragma unroll
        for (int rep = 0; rep < 2; rep++) {
            int brow = rep * 128 + srow;
            half8 bh = *(const half8*)(BT + brow * FEAT + kt + sg * 8);
            *(half8*)(lds + 8192 + brow * 64 + swz(brow, sg) * 16) = bh;
        }
        __syncthreads();

        half8 af[4], bf[4];
#pragma unroll
        for (int mi = 0; mi < 4; mi++) {
            int r = wr * 64 + mi * 16 + fr;
            af[mi] = *(const half8*)(lds + r * 64 + swz(r, fg) * 16);
        }
#pragma unroll
        for (int nj = 0; nj < 4; nj++) {
            int r = wc * 64 + nj * 16 + fr;
            bf[nj] = *(const half8*)(lds + 8192 + r * 64 + swz(r, fg) * 16);
        }
#pragma unroll
        for (int mi = 0; mi < 4; mi++)
#pragma unroll
            for (int nj = 0; nj < 4; nj++)
                acc[mi][nj] = __builtin_amdgcn_mfma_f32_16x16x32_f16(af[mi], bf[nj], acc[mi][nj], 0, 0, 0);
        __syncthreads();
    }

#pragma unroll
    for (int mi = 0; mi < 4; mi++) {
#pragma unroll
        for (int nj = 0; nj < 4; nj++) {
            int col = wc * 64 + nj * 16 + fr;
            float bv = bias[col];
#pragma unroll
            for (int r = 0; r < 4; r++) {
                long long row = by * 128 + wr * 64 + mi * 16 + fg * 4 + r;
                if (row < M) {
                    float v = fmaxf(acc[mi][nj][r] + bv, 0.f);
                    C[row * HID + col] = (_Float16)v;
                }
            }
        }
    }
}

// ---------- GEMM2: h[M][64](fp16), s0[M][64](fp16 = dinv*h) ----------
__global__ __launch_bounds__(512) void k_gemm2(const _Float16* __restrict__ A,
                                               const _Float16* __restrict__ BT,
                                               const float* __restrict__ bias,
                                               const float* __restrict__ dinv,
                                               _Float16* __restrict__ Hout,
                                               _Float16* __restrict__ S0, int M) {
    __shared__ __align__(16) char lds[16384 + 4096];
    const int t = threadIdx.x;
    const int wid = t >> 6, lane = t & 63;
    const int wr = wid >> 1, wc = wid & 1;
    const int srow = t >> 2, sg = t & 3;
    const int fr = lane & 15, fg = lane >> 4;
    const long long bm = blockIdx.x;

    f32x4 acc[4][2] = {};

    for (int kt = 0; kt < HID; kt += 32) {
#pragma unroll
        for (int rep = 0; rep < 2; rep++) {
            int ar = rep * 128 + srow;
            long long grow = bm * 256 + ar;
            if (grow >= M) grow = M - 1;
            half8 ah = *(const half8*)(A + grow * HID + kt + sg * 8);
            *(half8*)(lds + ar * 64 + swz(ar, sg) * 16) = ah;
        }
        if (t < 256) {
            int br = t >> 2;
            half8 bh = *(const half8*)(BT + br * HID + kt + sg * 8);
            *(half8*)(lds + 16384 + br * 64 + swz(br, sg) * 16) = bh;
        }
        __syncthreads();

        half8 af[4], bf[2];
#pragma unroll
        for (int mi = 0; mi < 4; mi++) {
            int r = wr * 64 + mi * 16 + fr;
            af[mi] = *(const half8*)(lds + r * 64 + swz(r, fg) * 16);
        }
#pragma unroll
        for (int nj = 0; nj < 2; nj++) {
            int r = wc * 32 + nj * 16 + fr;
            bf[nj] = *(const half8*)(lds + 16384 + r * 64 + swz(r, fg) * 16);
        }
#pragma unroll
        for (int mi = 0; mi < 4; mi++)
#pragma unroll
            for (int nj = 0; nj < 2; nj++)
                acc[mi][nj] = __builtin_amdgcn_mfma_f32_16x16x32_f16(af[mi], bf[nj], acc[mi][nj], 0, 0, 0);
        __syncthreads();
    }

#pragma unroll
    for (int mi = 0; mi < 4; mi++) {
#pragma unroll
        for (int nj = 0; nj < 2; nj++) {
            int col = wc * 32 + nj * 16 + fr;
            float bv = bias[col];
#pragma unroll
            for (int r = 0; r < 4; r++) {
                long long row = bm * 256 + wr * 64 + mi * 16 + fg * 4 + r;
                if (row < M) {
                    float o = acc[mi][nj][r] + bv;
                    Hout[row * CLS + col] = (_Float16)o;
                    S0[row * CLS + col] = (_Float16)(dinv[row] * o);
                }
            }
        }
    }
}

// ---------- propagation: one wave per node; 8 rows per gather instruction ----------
// lane = (g = lane>>3 edge subgroup 0..7, sl = lane&7 class-octet). One load
// instruction pulls 8 random 128B rows (8 lanes x 16B each); 16-deep main loop
// keeps 16 row transactions in flight per wave.
__global__ __launch_bounds__(256) void k_prop(const int* __restrict__ ccol,
                                              const int* __restrict__ offs,
                                              const float* __restrict__ dinv,
                                              const _Float16* __restrict__ src,
                                              const _Float16* __restrict__ h,
                                              _Float16* __restrict__ dst,
                                              float* __restrict__ out, int last) {
    int wid = (blockIdx.x << 2) + (threadIdx.x >> 6);
    int lane = threadIdx.x & 63;
    if (wid >= N_NODES) return;
    const int g = lane >> 3;
    const int sl = lane & 7;
    const int e0 = offs[wid], e1 = offs[wid + 1];
    float acc[8] = {};
    int e = e0;
    for (; e + 16 <= e1; e += 16) {
        int c0 = ccol[e + g];
        int c1 = ccol[e + 8 + g];
        half8 v0 = *(const half8*)(src + (long long)c0 * CLS + sl * 8);
        half8 v1 = *(const half8*)(src + (long long)c1 * CLS + sl * 8);
#pragma unroll
        for (int j = 0; j < 8; j++) acc[j] += (float)v0[j] + (float)v1[j];
    }
    if (e + 8 <= e1) {
        int c0 = ccol[e + g];
        half8 v0 = *(const half8*)(src + (long long)c0 * CLS + sl * 8);
#pragma unroll
        for (int j = 0; j < 8; j++) acc[j] += (float)v0[j];
        e += 8;
    }
    if (e < e1) {
        int idx = e + g;
        if (idx < e1) {
            int c = ccol[idx];
            half8 v = *(const half8*)(src + (long long)c * CLS + sl * 8);
#pragma unroll
            for (int j = 0; j < 8; j++) acc[j] += (float)v[j];
        }
    }
    // reduce across the 8 edge subgroups (lanes with same sl)
#pragma unroll
    for (int j = 0; j < 8; j++) {
        acc[j] += __shfl_xor(acc[j], 8);
        acc[j] += __shfl_xor(acc[j], 16);
        acc[j] += __shfl_xor(acc[j], 32);
    }

    float dr = dinv[wid];
    half8 hh = *(const half8*)(h + (long long)wid * CLS + sl * 8);
    float o[8];
#pragma unroll
    for (int j = 0; j < 8; j++) o[j] = 0.9f * dr * acc[j] + 0.1f * (float)hh[j];

    if (!last) {
        if (g == 0) {
            half8 ov;
#pragma unroll
            for (int j = 0; j < 8; j++) ov[j] = (_Float16)(dr * o[j]);
            *(half8*)(dst + (long long)wid * CLS + sl * 8) = ov;
        }
    } else {
        float m = o[0];
#pragma unroll
        for (int j = 1; j < 8; j++) m = fmaxf(m, o[j]);
        m = fmaxf(m, __shfl_xor(m, 1));
        m = fmaxf(m, __shfl_xor(m, 2));
        m = fmaxf(m, __shfl_xor(m, 4));
        float s = 0.f;
#pragma unroll
        for (int j = 0; j < 8; j++) s += expf(o[j] - m);
        s += __shfl_xor(s, 1);
        s += __shfl_xor(s, 2);
        s += __shfl_xor(s, 4);
        float ls = logf(s);
        if (g == 0) {
            float4 ov0 = make_float4(o[0] - m - ls, o[1] - m - ls, o[2] - m - ls, o[3] - m - ls);
            float4 ov1 = make_float4(o[4] - m - ls, o[5] - m - ls, o[6] - m - ls, o[7] - m - ls);
            *(float4*)(out + (long long)wid * CLS + sl * 8) = ov0;
            *(float4*)(out + (long long)wid * CLS + sl * 8 + 4) = ov1;
        }
    }
}

extern "C" void kernel_launch(void* const* d_in, const int* in_sizes, int n_in,
                              void* d_out, int out_size, void* d_ws, size_t ws_size,
                              hipStream_t stream) {
    const float* x  = (const float*)d_in[0];
    const void*  ei = d_in[1];
    const float* W1 = (const float*)d_in[2];
    const float* b1 = (const float*)d_in[3];
    const float* W2 = (const float*)d_in[4];
    const float* b2 = (const float*)d_in[5];
    float* out = (float*)d_out;

    char* p = (char*)d_ws;
    size_t off = 0;
    auto alloc = [&](size_t bytes) {
        char* q = p + off;
        off = (off + bytes + 255) & ~(size_t)255;
        return q;
    };
    int*      flag   = (int*)alloc(16);
    float*    dinv   = (float*)alloc((size_t)N_NODES * 4);
    int*      offs   = (int*)alloc((size_t)(N_NODES + 1) * 4);
    int*      bcntR  = (int*)alloc((NBUCK + 1) * 4);
    int*      bcntC  = (int*)alloc((NBUCK + 1) * 4);
    int*      bbaseR = (int*)alloc((NBUCK + 1) * 4);
    int*      bbaseC = (int*)alloc((NBUCK + 1) * 4);
    int*      cbase  = (int*)alloc((NBUCK + 1) * 4);
    int*      gcurR  = (int*)alloc((NBUCK + 1) * 4);
    int*      gcurC  = (int*)alloc((NBUCK + 1) * 4);
    unsigned long long* pairs = (unsigned long long*)alloc((size_t)N_EDGES * 8);
    int*      cvals  = (int*)alloc((size_t)N_EDGES * 4);
    int*      ccol   = (int*)alloc(((size_t)N_EDGES + N_NODES + 64) * 4);
    _Float16* h      = (_Float16*)alloc((size_t)N_NODES * CLS * 2);
    _Float16* s0     = (_Float16*)alloc((size_t)N_NODES * CLS * 2);
    _Float16* bufA   = (_Float16*)alloc((size_t)N_NODES * CLS * 2);
    _Float16* bufB   = (_Float16*)alloc((size_t)N_NODES * CLS * 2);
    _Float16* h1     = (_Float16*)alloc((size_t)N_NODES * HID * 2);
    _Float16* W1T    = (_Float16*)alloc((size_t)HID * FEAT * 2);
    _Float16* W2T    = (_Float16*)alloc((size_t)CLS * HID * 2);
    (void)ws_size;

    // graph build
    k_detect<<<1, 256, 0, stream>>>((const unsigned*)ei, flag);
    k_init<<<1, 256, 0, stream>>>(bcntR, bcntC);
    k_bhist<<<(N_EDGES + CHB - 1) / CHB, 256, 0, stream>>>(ei, flag, bcntR, bcntC);
    k_bscan<<<1, 64, 0, stream>>>(bcntR, bcntC, bbaseR, gcurR, bbaseC, gcurC, cbase, offs);
    k_binA<<<(N_EDGES + CH - 1) / CH, 256, 0, stream>>>(ei, flag, gcurR, gcurC, pairs, cvals);
    k_degB<<<NBUCK, 1024, 0, stream>>>(cvals, bbaseC, dinv);
    k_binB<<<NBUCK, 1024, 0, stream>>>(pairs, bbaseR, cbase, offs, ccol);

    // dense layers (fp16 MFMA)
    k_cvtW<<<512, 256, 0, stream>>>(W1, W2, W1T, W2T);
    k_gemm1<<<(N_NODES + 127) / 128, 512, 0, stream>>>(x, W1T, b1, h1, N_NODES);
    k_gemm2<<<(N_NODES + 255) / 256, 512, 0, stream>>>(h1, W2T, b2, dinv, h, s0, N_NODES);

    // K propagation steps; final step fuses log_softmax
    const int pgrid = (N_NODES + 3) / 4;
    _Float16* ping[2] = {bufA, bufB};
    for (int it = 0; it < K_ITER; it++) {
        const _Float16* src = (it == 0) ? s0 : ping[(it - 1) & 1];
        _Float16* dst = ping[it & 1];
        k_prop<<<pgrid, 256, 0, stream>>>(ccol, offs, dinv, src, h, dst, out, it == K_ITER - 1);
    }
}

// Round 7
// 791.529 us; speedup vs baseline: 3.4565x; 1.0415x over previous
//
#include <hip/hip_runtime.h>
#include <hip/hip_bf16.h>
#include <math.h>

#define N_NODES 100000
#define N_EDGES 3200000
#define FEAT 512
#define HID 256
#define CLS 64
#define K_ITER 10
#define NBUCK 196            // ceil(100000 / 512) node buckets of width 512
#define BSH 9                // bucket = r >> 9

typedef _Float16 half8 __attribute__((ext_vector_type(8)));
typedef float f32x4 __attribute__((ext_vector_type(4)));

// ---------- edge index access (int32 or int64, detected at runtime) ----------
__device__ __forceinline__ int edge_at(const void* e, int is64, long long idx) {
    return is64 ? (int)((const long long*)e)[idx] : ((const int*)e)[idx];
}

__global__ void k_detect(const unsigned* __restrict__ e, int* __restrict__ flag,
                         int* __restrict__ bcntR, int* __restrict__ bcntC) {
    __shared__ unsigned s[256];
    unsigned v = 0;
    for (int i = threadIdx.x; i < 4096; i += 256) v |= e[2 * i + 1];
    s[threadIdx.x] = v;
    __syncthreads();
    for (int off = 128; off; off >>= 1) {
        if (threadIdx.x < off) s[threadIdx.x] |= s[threadIdx.x + off];
        __syncthreads();
    }
    if (threadIdx.x == 0) flag[0] = (s[0] == 0) ? 1 : 0;
    if (threadIdx.x < NBUCK) { bcntR[threadIdx.x] = 0; bcntC[threadIdx.x] = 0; }
}

// ---------- pass 0: dual bucket histogram (r and c), no value atomics ----------
#define CHB 4096
__global__ __launch_bounds__(256) void k_bhist(const void* __restrict__ e,
                                               const int* __restrict__ flag,
                                               int* __restrict__ bcntR,
                                               int* __restrict__ bcntC) {
    __shared__ int lhR[NBUCK], lhC[NBUCK];
    for (int i = threadIdx.x; i < NBUCK; i += 256) { lhR[i] = 0; lhC[i] = 0; }
    __syncthreads();
    int is64 = flag[0];
    long long base = (long long)blockIdx.x * CHB;
    for (int j = threadIdx.x; j < CHB; j += 256) {
        long long i = base + j;
        if (i < N_EDGES) {
            int r = edge_at(e, is64, i);
            int c = edge_at(e, is64, (long long)N_EDGES + i);
            atomicAdd(&lhR[r >> BSH], 1);
            atomicAdd(&lhC[c >> BSH], 1);
        }
    }
    __syncthreads();
    for (int i = threadIdx.x; i < NBUCK; i += 256) {
        if (lhR[i]) atomicAdd(&bcntR[i], lhR[i]);
        if (lhC[i]) atomicAdd(&bcntC[i], lhC[i]);
    }
}

// ---------- bucket base scan (196 entries; trivial serial) ----------
__global__ void k_bscan(const int* __restrict__ bcntR, const int* __restrict__ bcntC,
                        int* __restrict__ bbaseR, int* __restrict__ gcurR,
                        int* __restrict__ bbaseC, int* __restrict__ gcurC,
                        int* __restrict__ cbase, int* __restrict__ offs) {
    if (threadIdx.x == 0) {
        int accE = 0, accC = 0, accCv = 0;
        for (int b = 0; b < NBUCK; b++) {
            bbaseR[b] = accE;
            gcurR[b] = accE;
            bbaseC[b] = accCv;
            gcurC[b] = accCv;
            cbase[b] = accC;
            int nb0 = b << BSH;
            int nn = (N_NODES - nb0 < 512) ? (N_NODES - nb0) : 512;
            accE += bcntR[b];
            accCv += bcntC[b];
            accC += bcntR[b] + nn;
        }
        bbaseR[NBUCK] = accE;
        bbaseC[NBUCK] = accCv;
        cbase[NBUCK] = accC;
        offs[N_NODES] = accC;
    }
}

// ---------- pass A: bin edges into bucket-contiguous runs ----------
// pairs entry (r-binned): (c << 9) | (r & 511)   [26 bits used]
#define CH 4096
__global__ __launch_bounds__(256) void k_binA(const void* __restrict__ e,
                                              const int* __restrict__ flag,
                                              int* __restrict__ gcurR,
                                              int* __restrict__ gcurC,
                                              unsigned* __restrict__ pairs,
                                              int* __restrict__ cvals) {
    __shared__ int lhR[NBUCK], gbR[NBUCK], lcR[NBUCK];
    __shared__ int lhC[NBUCK], gbC[NBUCK], lcC[NBUCK];
    for (int i = threadIdx.x; i < NBUCK; i += 256) { lhR[i] = 0; lhC[i] = 0; }
    __syncthreads();
    int is64 = flag[0];
    long long base = (long long)blockIdx.x * CH;
    // phase 1: local histograms
    for (int j = threadIdx.x; j < CH; j += 256) {
        long long i = base + j;
        if (i < N_EDGES) {
            int r = edge_at(e, is64, i);
            int c = edge_at(e, is64, (long long)N_EDGES + i);
            atomicAdd(&lhR[r >> BSH], 1);
            atomicAdd(&lhC[c >> BSH], 1);
        }
    }
    __syncthreads();
    // phase 2: reserve contiguous runs per bucket
    for (int i = threadIdx.x; i < NBUCK; i += 256) {
        lcR[i] = 0;
        lcC[i] = 0;
        gbR[i] = lhR[i] ? atomicAdd(&gcurR[i], lhR[i]) : 0;
        gbC[i] = lhC[i] ? atomicAdd(&gcurC[i], lhC[i]) : 0;
    }
    __syncthreads();
    // phase 3: place (re-read edges; L2-hot)
    for (int j = threadIdx.x; j < CH; j += 256) {
        long long i = base + j;
        if (i < N_EDGES) {
            int r = edge_at(e, is64, i);
            int c = edge_at(e, is64, (long long)N_EDGES + i);
            int b = r >> BSH;
            int pos = atomicAdd(&lcR[b], 1);
            pairs[(long long)gbR[b] + pos] = ((unsigned)c << 9) | (unsigned)(r & 511);
            int bc = c >> BSH;
            int posc = atomicAdd(&lcC[bc], 1);
            cvals[(long long)gbC[bc] + posc] = c;
        }
    }
}

// ---------- merged per-bucket pass: deg/dinv (blocks 0..195) + CSR build (196..391) ----------
__global__ __launch_bounds__(1024) void k_bins(const int* __restrict__ cvals,
                                               const int* __restrict__ bbaseC,
                                               float* __restrict__ dinv,
                                               const unsigned* __restrict__ pairs,
                                               const int* __restrict__ bbaseR,
                                               const int* __restrict__ cbase,
                                               int* __restrict__ offs,
                                               int* __restrict__ ccol) {
    __shared__ int cnt[512], cur[512], s[512];
    const int t = threadIdx.x;
    if (blockIdx.x < NBUCK) {
        // degree count over c occurrences
        const int b = blockIdx.x;
        const int nb0 = b << BSH;
        const int nn = (N_NODES - nb0 < 512) ? (N_NODES - nb0) : 512;
        if (t < 512) cnt[t] = 1;  // self loop
        __syncthreads();
        const int e0 = bbaseC[b], e1 = bbaseC[b + 1];
        for (int i = e0 + t; i < e1; i += 1024) {
            atomicAdd(&cnt[cvals[i] - nb0], 1);
        }
        __syncthreads();
        if (t < nn) dinv[nb0 + t] = rsqrtf((float)cnt[t]);
        return;
    }
    // CSR build
    const int b = blockIdx.x - NBUCK;
    const int nb0 = b << BSH;
    const int nn = (N_NODES - nb0 < 512) ? (N_NODES - nb0) : 512;
    if (t < 512) cnt[t] = (t < nn) ? 1 : 0;  // self loop
    __syncthreads();
    const int e0 = bbaseR[b], e1 = bbaseR[b + 1];
    for (int i = e0 + t; i < e1; i += 1024) {
        atomicAdd(&cnt[pairs[i] & 511u], 1);
    }
    __syncthreads();
    // exclusive scan of cnt[0..511]
    int v = (t < 512) ? cnt[t] : 0;
    if (t < 512) s[t] = v;
    __syncthreads();
    for (int off = 1; off < 512; off <<= 1) {
        int a = 0;
        if (t < 512 && t >= off) a = s[t - off];
        __syncthreads();
        if (t < 512) s[t] += a;
        __syncthreads();
    }
    const int cb = cbase[b];
    if (t < 512) {
        int excl = s[t] - v;
        cur[t] = excl;
        if (t < nn) {
            offs[nb0 + t] = cb + excl;
            ccol[cb + excl] = nb0 + t;  // self loop entry
            cur[t] = excl + 1;
        }
    }
    __syncthreads();
    for (int i = e0 + t; i < e1; i += 1024) {
        unsigned p = pairs[i];
        int r = (int)(p & 511u);
        int c = (int)(p >> 9);
        int pos = atomicAdd(&cur[r], 1);
        ccol[cb + pos] = c;
    }
}

// ---------- weight transpose + fp16 convert ----------
__global__ void k_cvtW(const float* __restrict__ W1, const float* __restrict__ W2,
                       _Float16* __restrict__ W1T, _Float16* __restrict__ W2T) {
    int i = blockIdx.x * 256 + threadIdx.x;
    if (i < 256 * 512) {
        int n = i >> 9, k = i & 511;
        W1T[i] = (_Float16)W1[k * 256 + n];
    }
    if (i < 64 * 256) {
        int n = i >> 8, k = i & 255;
        W2T[i] = (_Float16)W2[k * 64 + n];
    }
}

// swizzle helper: physical granule for (row, logical granule)
__device__ __forceinline__ int swz(int row, int g) {
    return g ^ (row & 3) ^ ((row >> 2) & 3);
}

// ---------- GEMM1: h1[M][256](fp16) = relu(x[M][512](fp32) @ W1 + b1) ----------
__global__ __launch_bounds__(512) void k_gemm1(const float* __restrict__ A,
                                               const _Float16* __restrict__ BT,
                                               const float* __restrict__ bias,
                                               _Float16* __restrict__ C, int M) {
    __shared__ __align__(16) char lds[8192 + 16384];
    const int t = threadIdx.x;
    const int wid = t >> 6, lane = t & 63;
    const int wr = wid >> 2, wc = wid & 3;
    const int srow = t >> 2, sg = t & 3;
    const int fr = lane & 15, fg = lane >> 4;
    const long long by = blockIdx.x;

    f32x4 acc[4][4] = {};
    const long long arow = by * 128 + srow;
    const bool avalid = (arow < M);
    const float* ap0 = A + arow * FEAT + sg * 8;

    for (int kt = 0; kt < FEAT; kt += 32) {
        float4 a0 = make_float4(0.f, 0.f, 0.f, 0.f), a1 = a0;
        if (avalid) {
            const float* ap = ap0 + kt;
            a0 = *(const float4*)ap;
            a1 = *(const float4*)(ap + 4);
        }
        half8 ah;
        ah[0] = (_Float16)a0.x; ah[1] = (_Float16)a0.y;
        ah[2] = (_Float16)a0.z; ah[3] = (_Float16)a0.w;
        ah[4] = (_Float16)a1.x; ah[5] = (_Float16)a1.y;
        ah[6] = (_Float16)a1.z; ah[7] = (_Float16)a1.w;
        *(half8*)(lds + srow * 64 + swz(srow, sg) * 16) = ah;
#pragma unroll
        for (int rep = 0; rep < 2; rep++) {
            int brow = rep * 128 + srow;
            half8 bh = *(const half8*)(BT + brow * FEAT + kt + sg * 8);
            *(half8*)(lds + 8192 + brow * 64 + swz(brow, sg) * 16) = bh;
        }
        __syncthreads();

        half8 af[4], bf[4];
#pragma unroll
        for (int mi = 0; mi < 4; mi++) {
            int r = wr * 64 + mi * 16 + fr;
            af[mi] = *(const half8*)(lds + r * 64 + swz(r, fg) * 16);
        }
#pragma unroll
        for (int nj = 0; nj < 4; nj++) {
            int r = wc * 64 + nj * 16 + fr;
            bf[nj] = *(const half8*)(lds + 8192 + r * 64 + swz(r, fg) * 16);
        }
#pragma unroll
        for (int mi = 0; mi < 4; mi++)
#pragma unroll
            for (int nj = 0; nj < 4; nj++)
                acc[mi][nj] = __builtin_amdgcn_mfma_f32_16x16x32_f16(af[mi], bf[nj], acc[mi][nj], 0, 0, 0);
        __syncthreads();
    }

#pragma unroll
    for (int mi = 0; mi < 4; mi++) {
#pragma unroll
        for (int nj = 0; nj < 4; nj++) {
            int col = wc * 64 + nj * 16 + fr;
            float bv = bias[col];
#pragma unroll
            for (int r = 0; r < 4; r++) {
                long long row = by * 128 + wr * 64 + mi * 16 + fg * 4 + r;
                if (row < M) {
                    float v = fmaxf(acc[mi][nj][r] + bv, 0.f);
                    C[row * HID + col] = (_Float16)v;
                }
            }
        }
    }
}

// ---------- GEMM2: h[M][64](fp16), s0[M][64](fp16 = dinv*h) ----------
__global__ __launch_bounds__(512) void k_gemm2(const _Float16* __restrict__ A,
                                               const _Float16* __restrict__ BT,
                                               const float* __restrict__ bias,
                                               const float* __restrict__ dinv,
                                               _Float16* __restrict__ Hout,
                                               _Float16* __restrict__ S0, int M) {
    __shared__ __align__(16) char lds[16384 + 4096];
    const int t = threadIdx.x;
    const int wid = t >> 6, lane = t & 63;
    const int wr = wid >> 1, wc = wid & 1;
    const int srow = t >> 2, sg = t & 3;
    const int fr = lane & 15, fg = lane >> 4;
    const long long bm = blockIdx.x;

    f32x4 acc[4][2] = {};

    for (int kt = 0; kt < HID; kt += 32) {
#pragma unroll
        for (int rep = 0; rep < 2; rep++) {
            int ar = rep * 128 + srow;
            long long grow = bm * 256 + ar;
            if (grow >= M) grow = M - 1;
            half8 ah = *(const half8*)(A + grow * HID + kt + sg * 8);
            *(half8*)(lds + ar * 64 + swz(ar, sg) * 16) = ah;
        }
        if (t < 256) {
            int br = t >> 2;
            half8 bh = *(const half8*)(BT + br * HID + kt + sg * 8);
            *(half8*)(lds + 16384 + br * 64 + swz(br, sg) * 16) = bh;
        }
        __syncthreads();

        half8 af[4], bf[2];
#pragma unroll
        for (int mi = 0; mi < 4; mi++) {
            int r = wr * 64 + mi * 16 + fr;
            af[mi] = *(const half8*)(lds + r * 64 + swz(r, fg) * 16);
        }
#pragma unroll
        for (int nj = 0; nj < 2; nj++) {
            int r = wc * 32 + nj * 16 + fr;
            bf[nj] = *(const half8*)(lds + 16384 + r * 64 + swz(r, fg) * 16);
        }
#pragma unroll
        for (int mi = 0; mi < 4; mi++)
#pragma unroll
            for (int nj = 0; nj < 2; nj++)
                acc[mi][nj] = __builtin_amdgcn_mfma_f32_16x16x32_f16(af[mi], bf[nj], acc[mi][nj], 0, 0, 0);
        __syncthreads();
    }

#pragma unroll
    for (int mi = 0; mi < 4; mi++) {
#pragma unroll
        for (int nj = 0; nj < 2; nj++) {
            int col = wc * 32 + nj * 16 + fr;
            float bv = bias[col];
#pragma unroll
            for (int r = 0; r < 4; r++) {
                long long row = bm * 256 + wr * 64 + mi * 16 + fg * 4 + r;
                if (row < M) {
                    float o = acc[mi][nj][r] + bv;
                    Hout[row * CLS + col] = (_Float16)o;
                    S0[row * CLS + col] = (_Float16)(dinv[row] * o);
                }
            }
        }
    }
}

// ---------- propagation: one wave per node; 8 rows per gather instruction ----------
// lane = (g = lane>>3 edge subgroup 0..7, sl = lane&7 class-octet). 32-deep main
// loop keeps 4 gather instructions (32 row transactions) in flight per wave.
__global__ __launch_bounds__(256) void k_prop(const int* __restrict__ ccol,
                                              const int* __restrict__ offs,
                                              const float* __restrict__ dinv,
                                              const _Float16* __restrict__ src,
                                              const _Float16* __restrict__ h,
                                              _Float16* __restrict__ dst,
                                              float* __restrict__ out, int last) {
    int wid = (blockIdx.x << 2) + (threadIdx.x >> 6);
    int lane = threadIdx.x & 63;
    if (wid >= N_NODES) return;
    const int g = lane >> 3;
    const int sl = lane & 7;
    const int e0 = offs[wid], e1 = offs[wid + 1];
    float acc[8] = {};
    int e = e0;
    for (; e + 32 <= e1; e += 32) {
        int c0 = ccol[e + g];
        int c1 = ccol[e + 8 + g];
        int c2 = ccol[e + 16 + g];
        int c3 = ccol[e + 24 + g];
        half8 v0 = *(const half8*)(src + (long long)c0 * CLS + sl * 8);
        half8 v1 = *(const half8*)(src + (long long)c1 * CLS + sl * 8);
        half8 v2 = *(const half8*)(src + (long long)c2 * CLS + sl * 8);
        half8 v3 = *(const half8*)(src + (long long)c3 * CLS + sl * 8);
#pragma unroll
        for (int j = 0; j < 8; j++)
            acc[j] += ((float)v0[j] + (float)v1[j]) + ((float)v2[j] + (float)v3[j]);
    }
    if (e + 16 <= e1) {
        int c0 = ccol[e + g];
        int c1 = ccol[e + 8 + g];
        half8 v0 = *(const half8*)(src + (long long)c0 * CLS + sl * 8);
        half8 v1 = *(const half8*)(src + (long long)c1 * CLS + sl * 8);
#pragma unroll
        for (int j = 0; j < 8; j++) acc[j] += (float)v0[j] + (float)v1[j];
        e += 16;
    }
    if (e + 8 <= e1) {
        int c0 = ccol[e + g];
        half8 v0 = *(const half8*)(src + (long long)c0 * CLS + sl * 8);
#pragma unroll
        for (int j = 0; j < 8; j++) acc[j] += (float)v0[j];
        e += 8;
    }
    if (e < e1) {
        int idx = e + g;
        if (idx < e1) {
            int c = ccol[idx];
            half8 v = *(const half8*)(src + (long long)c * CLS + sl * 8);
#pragma unroll
            for (int j = 0; j < 8; j++) acc[j] += (float)v[j];
        }
    }
    // reduce across the 8 edge subgroups (lanes with same sl)
#pragma unroll
    for (int j = 0; j < 8; j++) {
        acc[j] += __shfl_xor(acc[j], 8);
        acc[j] += __shfl_xor(acc[j], 16);
        acc[j] += __shfl_xor(acc[j], 32);
    }

    float dr = dinv[wid];
    half8 hh = *(const half8*)(h + (long long)wid * CLS + sl * 8);
    float o[8];
#pragma unroll
    for (int j = 0; j < 8; j++) o[j] = 0.9f * dr * acc[j] + 0.1f * (float)hh[j];

    if (!last) {
        if (g == 0) {
            half8 ov;
#pragma unroll
            for (int j = 0; j < 8; j++) ov[j] = (_Float16)(dr * o[j]);
            *(half8*)(dst + (long long)wid * CLS + sl * 8) = ov;
        }
    } else {
        float m = o[0];
#pragma unroll
        for (int j = 1; j < 8; j++) m = fmaxf(m, o[j]);
        m = fmaxf(m, __shfl_xor(m, 1));
        m = fmaxf(m, __shfl_xor(m, 2));
        m = fmaxf(m, __shfl_xor(m, 4));
        float s = 0.f;
#pragma unroll
        for (int j = 0; j < 8; j++) s += expf(o[j] - m);
        s += __shfl_xor(s, 1);
        s += __shfl_xor(s, 2);
        s += __shfl_xor(s, 4);
        float ls = logf(s);
        if (g == 0) {
            float4 ov0 = make_float4(o[0] - m - ls, o[1] - m - ls, o[2] - m - ls, o[3] - m - ls);
            float4 ov1 = make_float4(o[4] - m - ls, o[5] - m - ls, o[6] - m - ls, o[7] - m - ls);
            *(float4*)(out + (long long)wid * CLS + sl * 8) = ov0;
            *(float4*)(out + (long long)wid * CLS + sl * 8 + 4) = ov1;
        }
    }
}

extern "C" void kernel_launch(void* const* d_in, const int* in_sizes, int n_in,
                              void* d_out, int out_size, void* d_ws, size_t ws_size,
                              hipStream_t stream) {
    const float* x  = (const float*)d_in[0];
    const void*  ei = d_in[1];
    const float* W1 = (const float*)d_in[2];
    const float* b1 = (const float*)d_in[3];
    const float* W2 = (const float*)d_in[4];
    const float* b2 = (const float*)d_in[5];
    float* out = (float*)d_out;

    char* p = (char*)d_ws;
    size_t off = 0;
    auto alloc = [&](size_t bytes) {
        char* q = p + off;
        off = (off + bytes + 255) & ~(size_t)255;
        return q;
    };
    int*      flag   = (int*)alloc(16);
    float*    dinv   = (float*)alloc((size_t)N_NODES * 4);
    int*      offs   = (int*)alloc((size_t)(N_NODES + 1) * 4);
    int*      bcntR  = (int*)alloc((NBUCK + 1) * 4);
    int*      bcntC  = (int*)alloc((NBUCK + 1) * 4);
    int*      bbaseR = (int*)alloc((NBUCK + 1) * 4);
    int*      bbaseC = (int*)alloc((NBUCK + 1) * 4);
    int*      cbase  = (int*)alloc((NBUCK + 1) * 4);
    int*      gcurR  = (int*)alloc((NBUCK + 1) * 4);
    int*      gcurC  = (int*)alloc((NBUCK + 1) * 4);
    unsigned* pairs  = (unsigned*)alloc((size_t)N_EDGES * 4);
    int*      cvals  = (int*)alloc((size_t)N_EDGES * 4);
    int*      ccol   = (int*)alloc(((size_t)N_EDGES + N_NODES + 64) * 4);
    _Float16* h      = (_Float16*)alloc((size_t)N_NODES * CLS * 2);
    _Float16* s0     = (_Float16*)alloc((size_t)N_NODES * CLS * 2);
    _Float16* bufA   = (_Float16*)alloc((size_t)N_NODES * CLS * 2);
    _Float16* bufB   = (_Float16*)alloc((size_t)N_NODES * CLS * 2);
    _Float16* h1     = (_Float16*)alloc((size_t)N_NODES * HID * 2);
    _Float16* W1T    = (_Float16*)alloc((size_t)HID * FEAT * 2);
    _Float16* W2T    = (_Float16*)alloc((size_t)CLS * HID * 2);
    (void)ws_size;

    // graph build
    k_detect<<<1, 256, 0, stream>>>((const unsigned*)ei, flag, bcntR, bcntC);
    k_bhist<<<(N_EDGES + CHB - 1) / CHB, 256, 0, stream>>>(ei, flag, bcntR, bcntC);
    k_bscan<<<1, 64, 0, stream>>>(bcntR, bcntC, bbaseR, gcurR, bbaseC, gcurC, cbase, offs);
    k_binA<<<(N_EDGES + CH - 1) / CH, 256, 0, stream>>>(ei, flag, gcurR, gcurC, pairs, cvals);
    k_bins<<<2 * NBUCK, 1024, 0, stream>>>(cvals, bbaseC, dinv, pairs, bbaseR, cbase, offs, ccol);

    // dense layers (fp16 MFMA)
    k_cvtW<<<512, 256, 0, stream>>>(W1, W2, W1T, W2T);
    k_gemm1<<<(N_NODES + 127) / 128, 512, 0, stream>>>(x, W1T, b1, h1, N_NODES);
    k_gemm2<<<(N_NODES + 255) / 256, 512, 0, stream>>>(h1, W2T, b2, dinv, h, s0, N_NODES);

    // K propagation steps; final step fuses log_softmax
    const int pgrid = (N_NODES + 3) / 4;
    _Float16* ping[2] = {bufA, bufB};
    for (int it = 0; it < K_ITER; it++) {
        const _Float16* src = (it == 0) ? s0 : ping[(it - 1) & 1];
        _Float16* dst = ping[it & 1];
        k_prop<<<pgrid, 256, 0, stream>>>(ccol, offs, dinv, src, h, dst, out, it == K_ITER - 1);
    }
}